// Round 2
// baseline (21845.731 us; speedup 1.0000x reference)
//
#include <hip/hip_runtime.h>
#include <cstdint>

constexpr int Nn = 60000;
constexpr int Ee = 240000;
constexpr int Hh = 256;
constexpr int Mm = 64;
constexpr int F1c = 12;
constexpr int Lc = 4;
constexpr int NLc = 3;
constexpr int Gc = 2000;
constexpr float EPSc = 1e-5f;

// ---------------- embedding: x[n,c] = sum_j x_tab[x_idx[n,j], c] ----------------
__global__ void embed_x_kernel(const int* __restrict__ xidx, const float* __restrict__ xtab,
                               float* __restrict__ x) {
    int n = blockIdx.x;
    int c = threadIdx.x;
    __shared__ int idx[9];
    if (c < 9) idx[c] = xidx[n * 9 + c];
    __syncthreads();
    float s = 0.f;
#pragma unroll
    for (int j = 0; j < 9; j++) s += xtab[idx[j] * Hh + c];
    x[(size_t)n * Hh + c] = s;
}

// ---------------- graph segment boundaries via binary search (batch sorted) -------
__global__ void seg_bounds_kernel(const int* __restrict__ batch, int* __restrict__ gstart) {
    int g = blockIdx.x * 256 + threadIdx.x;
    if (g > Gc) return;
    if (g == Gc) { gstart[Gc] = Nn; return; }
    int lo = 0, hi = Nn;
    while (lo < hi) { int mid = (lo + hi) >> 1; if (batch[mid] < g) lo = mid + 1; else hi = mid; }
    gstart[g] = lo;
}

// ---------------- column sum / sumsq over [rows, 256] (node BatchNorm) ------------
__global__ void colstats_kernel(const float* __restrict__ A, long total,
                                float* __restrict__ sum, float* __restrict__ sq) {
    long i0 = (long)blockIdx.x * blockDim.x + threadIdx.x;
    long stride = (long)gridDim.x * blockDim.x;   // multiple of 256 -> fixed col
    float s = 0.f, q = 0.f;
    for (long i = i0; i < total; i += stride) { float v = A[i]; s += v; q += v * v; }
    int col = (int)(i0 & 255);
    atomicAdd(&sum[col], s);
    atomicAdd(&sq[col], q);
}

// ---------------- BN apply + ReLU over [rows, 256] --------------------------------
__global__ void bn_relu_kernel(const float* __restrict__ A, float* __restrict__ outp,
                               const float* __restrict__ sum, const float* __restrict__ sq,
                               const float* __restrict__ g, const float* __restrict__ be,
                               float rinv, long total) {
    long i = (long)blockIdx.x * 256 + threadIdx.x;
    if (i >= total) return;
    int col = (int)(i & 255);
    float m = sum[col] * rinv;
    float var = sq[col] * rinv - m * m;
    float v = (A[i] - m) * rsqrtf(var + EPSc) * g[col] + be[col];
    outp[i] = fmaxf(v, 0.f);
}

// ------- edge-feature stats: recompute U = feat@W1 + b on the fly, accumulate -----
__global__ void feat_stats_kernel(const float* __restrict__ F, const float* __restrict__ W,
                                  const float* __restrict__ b, int K,
                                  float* __restrict__ sum, float* __restrict__ sq) {
    __shared__ float Wsh[F1c * Mm];
    __shared__ float bsh[Mm];
    int tid = threadIdx.x;
    for (int i = tid; i < K * Mm; i += 256) Wsh[i] = W[i];
    if (tid < Mm) bsh[tid] = b[tid];
    __syncthreads();
    long total = (long)Ee * Mm;
    long i0 = (long)blockIdx.x * 256 + tid;
    long stride = (long)gridDim.x * 256;          // multiple of 64 -> fixed col
    float s = 0.f, q = 0.f;
    for (long i = i0; i < total; i += stride) {
        int r = (int)(i >> 6), m = (int)(i & 63);
        const float* fr = F + (size_t)r * K;
        float u = bsh[m];
        for (int k = 0; k < K; k++) u += fr[k] * Wsh[k * Mm + m];
        s += u; q += u * u;
    }
    int m0 = (int)(i0 & 63);
    atomicAdd(&sum[m0], s);
    atomicAdd(&sq[m0], q);
}

// ------- per-chunk: Uc = relu(BN(feat@W1 + b)) -------------------------------------
__global__ void feat_bn_kernel(const float* __restrict__ F, const float* __restrict__ W,
                               const float* __restrict__ b, int K,
                               const float* __restrict__ sum, const float* __restrict__ sq,
                               const float* __restrict__ g, const float* __restrict__ be,
                               float rinv, float* __restrict__ Uc, int c0, int ec) {
    __shared__ float Wsh[F1c * Mm];
    __shared__ float bsh[Mm];
    int tid = threadIdx.x;
    for (int i = tid; i < K * Mm; i += 256) Wsh[i] = W[i];
    if (tid < Mm) bsh[tid] = b[tid];
    __syncthreads();
    int i = blockIdx.x * 256 + tid;
    if (i >= ec * Mm) return;
    int rl = i >> 6, m = i & 63;
    const float* fr = F + (size_t)(c0 + rl) * K;
    float u = bsh[m];
    for (int k = 0; k < K; k++) u += fr[k] * Wsh[k * Mm + m];
    float mu = sum[m] * rinv;
    float var = sq[m] * rinv - mu * mu;
    float v = (u - mu) * rsqrtf(var + EPSc) * g[m] + be[m];
    Uc[i] = fmaxf(v, 0.f);
}

// ---------------- main SGEMM: C = act(A1@W1 [+ A2@W2] + bias) [+ res] -------------
// A row-major (lda), W row-major K x 256. 128x128 tile, 8x8/thread. res stride 256.
__global__ __launch_bounds__(256) void gemm_kernel(
    const float* __restrict__ A1, int lda1, const float* __restrict__ W1,
    const float* __restrict__ A2, int lda2, const float* __restrict__ W2,
    const float* __restrict__ bias, const float* __restrict__ res,
    float* __restrict__ C, int ldc,
    int rows, int K1, int Ktot, int do_relu) {
    __shared__ float As[16][128];
    __shared__ float Ws[16][128];
    int tid = threadIdx.x;
    int tx = tid & 15;
    int ty = tid >> 4;
    int r0 = blockIdx.x * 128;
    int j0 = blockIdx.y * 128;

    float acc[8][8];
#pragma unroll
    for (int i = 0; i < 8; i++)
#pragma unroll
        for (int j = 0; j < 8; j++) acc[i][j] = 0.f;

    int arow = tid >> 1;            // 0..127
    int ak = (tid & 1) * 8;         // 0 or 8
    int wcol = tid & 127;
    int wkb = (tid >> 7) * 8;       // 0 or 8

    for (int kt = 0; kt < Ktot; kt += 16) {
        const float* A; int lda; int koff;
        if (kt < K1) { A = A1; lda = lda1; koff = kt; }
        else         { A = A2; lda = lda2; koff = kt - K1; }
        int grow = r0 + arow;
        float4 av0 = make_float4(0.f, 0.f, 0.f, 0.f);
        float4 av1 = make_float4(0.f, 0.f, 0.f, 0.f);
        if (grow < rows) {
            const float* ap = A + (size_t)grow * lda + koff + ak;
            av0 = *(const float4*)ap;
            av1 = *(const float4*)(ap + 4);
        }
        As[ak + 0][arow] = av0.x; As[ak + 1][arow] = av0.y;
        As[ak + 2][arow] = av0.z; As[ak + 3][arow] = av0.w;
        As[ak + 4][arow] = av1.x; As[ak + 5][arow] = av1.y;
        As[ak + 6][arow] = av1.z; As[ak + 7][arow] = av1.w;

        const float* W; int wkoff;
        if (kt < K1) { W = W1; wkoff = kt; }
        else         { W = W2; wkoff = kt - K1; }
#pragma unroll
        for (int i = 0; i < 8; i++) {
            int kk = wkb + i;
            Ws[kk][wcol] = W[(size_t)(wkoff + kk) * 256 + j0 + wcol];
        }
        __syncthreads();

#pragma unroll
        for (int kk = 0; kk < 16; kk++) {
            float ar[8], br[8];
            *(float4*)&ar[0] = *(const float4*)&As[kk][ty * 8];
            *(float4*)&ar[4] = *(const float4*)&As[kk][ty * 8 + 4];
            *(float4*)&br[0] = *(const float4*)&Ws[kk][tx * 8];
            *(float4*)&br[4] = *(const float4*)&Ws[kk][tx * 8 + 4];
#pragma unroll
            for (int i = 0; i < 8; i++)
#pragma unroll
                for (int j = 0; j < 8; j++) acc[i][j] += ar[i] * br[j];
        }
        __syncthreads();
    }

#pragma unroll
    for (int i = 0; i < 8; i++) {
        int r = r0 + ty * 8 + i;
        if (r >= rows) continue;
#pragma unroll
        for (int j = 0; j < 8; j++) {
            int c = j0 + tx * 8 + j;
            float v = acc[i][j] + bias[c];
            if (do_relu) v = fmaxf(v, 0.f);
            if (res) v += res[(size_t)r * 256 + c];
            C[(size_t)r * ldc + c] = v;
        }
    }
}

// ------- fused edge-weight GEMM + scatter:
//   w[e, :] = relu(Uc[e,:] @ W2 + b2);  agg[dst[e], :] += xl[src[e], :] * w[e, :]
__global__ __launch_bounds__(256) void gemm_scatter_kernel(
    const float* __restrict__ U, const float* __restrict__ W,
    const float* __restrict__ bias, const float* __restrict__ xl,
    const int* __restrict__ ei, float* __restrict__ agg,
    int c0, int ec) {
    __shared__ float As[16][128];
    __shared__ float Ws[16][128];
    int tid = threadIdx.x;
    int tx = tid & 15;
    int ty = tid >> 4;
    int r0 = blockIdx.x * 128;
    int j0 = blockIdx.y * 128;

    float acc[8][8];
#pragma unroll
    for (int i = 0; i < 8; i++)
#pragma unroll
        for (int j = 0; j < 8; j++) acc[i][j] = 0.f;

    int arow = tid >> 1;
    int ak = (tid & 1) * 8;
    int wcol = tid & 127;
    int wkb = (tid >> 7) * 8;

    for (int kt = 0; kt < 64; kt += 16) {
        int grow = r0 + arow;
        float4 av0 = make_float4(0.f, 0.f, 0.f, 0.f);
        float4 av1 = make_float4(0.f, 0.f, 0.f, 0.f);
        if (grow < ec) {
            const float* ap = U + (size_t)grow * Mm + kt + ak;
            av0 = *(const float4*)ap;
            av1 = *(const float4*)(ap + 4);
        }
        As[ak + 0][arow] = av0.x; As[ak + 1][arow] = av0.y;
        As[ak + 2][arow] = av0.z; As[ak + 3][arow] = av0.w;
        As[ak + 4][arow] = av1.x; As[ak + 5][arow] = av1.y;
        As[ak + 6][arow] = av1.z; As[ak + 7][arow] = av1.w;
#pragma unroll
        for (int i = 0; i < 8; i++) {
            int kk = wkb + i;
            Ws[kk][wcol] = W[(size_t)(kt + kk) * 256 + j0 + wcol];
        }
        __syncthreads();
#pragma unroll
        for (int kk = 0; kk < 16; kk++) {
            float ar[8], br[8];
            *(float4*)&ar[0] = *(const float4*)&As[kk][ty * 8];
            *(float4*)&ar[4] = *(const float4*)&As[kk][ty * 8 + 4];
            *(float4*)&br[0] = *(const float4*)&Ws[kk][tx * 8];
            *(float4*)&br[4] = *(const float4*)&Ws[kk][tx * 8 + 4];
#pragma unroll
            for (int i = 0; i < 8; i++)
#pragma unroll
                for (int j = 0; j < 8; j++) acc[i][j] += ar[i] * br[j];
        }
        __syncthreads();
    }

    float bj[8];
#pragma unroll
    for (int j = 0; j < 8; j++) bj[j] = bias[j0 + tx * 8 + j];

#pragma unroll
    for (int i = 0; i < 8; i++) {
        int r = r0 + ty * 8 + i;
        if (r >= ec) continue;
        int e = c0 + r;
        int src = ei[e];
        int dst = ei[Ee + e];
        const float* xr = xl + (size_t)src * Hh + j0 + tx * 8;
        float4 x0 = *(const float4*)xr;
        float4 x1 = *(const float4*)(xr + 4);
        float xv[8] = {x0.x, x0.y, x0.z, x0.w, x1.x, x1.y, x1.z, x1.w};
        float* ar = agg + (size_t)dst * Hh + j0 + tx * 8;
#pragma unroll
        for (int j = 0; j < 8; j++) {
            float w = fmaxf(acc[i][j] + bj[j], 0.f);
            atomicAdd(ar + j, xv[j] * w);
        }
    }
}

// ---------------- GraphNorm ----------------
__global__ void gn_mean_kernel(const float* __restrict__ h, const int* __restrict__ gstart,
                               float* __restrict__ mean) {
    int g = blockIdx.x, c = threadIdx.x;
    int s = gstart[g], e = gstart[g + 1];
    float acc = 0.f;
    for (int n = s; n < e; n++) acc += h[(size_t)n * Hh + c];
    float cnt = (float)((e - s) > 1 ? (e - s) : 1);
    mean[(size_t)g * Hh + c] = acc / cnt;
}

__global__ void gn_out_kernel(const float* __restrict__ h, const float* __restrict__ mean,
                              const int* __restrict__ batch, const float* __restrict__ ms,
                              float* __restrict__ outp) {
    long i = (long)blockIdx.x * 256 + threadIdx.x;
    if (i >= (long)Nn * Hh) return;
    int n = (int)(i >> 8);
    int c = (int)(i & 255);
    outp[i] = h[i] - ms[c] * mean[(size_t)batch[n] * Hh + c];
}

__global__ void gn_rstd_kernel(const float* __restrict__ outp, const int* __restrict__ gstart,
                               float* __restrict__ rstd) {
    int g = blockIdx.x, c = threadIdx.x;
    int s = gstart[g], e = gstart[g + 1];
    float acc = 0.f;
    for (int n = s; n < e; n++) { float v = outp[(size_t)n * Hh + c]; acc += v * v; }
    float cnt = (float)((e - s) > 1 ? (e - s) : 1);
    rstd[(size_t)g * Hh + c] = rsqrtf(acc / cnt + EPSc);
}

__global__ void gn_apply_kernel(float* __restrict__ outp, const float* __restrict__ rstd,
                                const int* __restrict__ batch, const float* __restrict__ w,
                                const float* __restrict__ b) {
    long i = (long)blockIdx.x * 256 + threadIdx.x;
    if (i >= (long)Nn * Hh) return;
    int n = (int)(i >> 8);
    int c = (int)(i & 255);
    outp[i] = outp[i] * rstd[(size_t)batch[n] * Hh + c] * w[c] + b[c];
}

// =====================================================================================
extern "C" void kernel_launch(void* const* d_in, const int* in_sizes, int n_in,
                              void* d_out, int out_size, void* d_ws, size_t ws_size,
                              hipStream_t stream) {
    const int* x_idx      = (const int*)d_in[0];
    const int* edge_index = (const int*)d_in[2];
    const int* batch      = (const int*)d_in[3];
    const float* feature1 = (const float*)d_in[4];
    const float* feature2 = (const float*)d_in[5];
    const float* x_tab    = (const float*)d_in[6];
    const float* linx_w   = (const float*)d_in[8];
    const float* linx_b   = (const float*)d_in[9];
    const float* linx_g   = (const float*)d_in[10];
    const float* linx_be  = (const float*)d_in[11];
    const float* f1_w1    = (const float*)d_in[12];
    const float* f1_b1    = (const float*)d_in[13];
    const float* f1_g     = (const float*)d_in[14];
    const float* f1_be    = (const float*)d_in[15];
    const float* f1_w2    = (const float*)d_in[16];
    const float* f1_b2    = (const float*)d_in[17];
    const float* f2_w1    = (const float*)d_in[18];
    const float* f2_b1    = (const float*)d_in[19];
    const float* f2_g     = (const float*)d_in[20];
    const float* f2_be    = (const float*)d_in[21];
    const float* f2_w2    = (const float*)d_in[22];
    const float* f2_b2    = (const float*)d_in[23];
    const float* c1_rel_w  = (const float*)d_in[24];
    const float* c1_rel_b  = (const float*)d_in[25];
    const float* c1_root_w = (const float*)d_in[26];
    const float* c2_rel_w  = (const float*)d_in[27];
    const float* c2_rel_b  = (const float*)d_in[28];
    const float* c2_root_w = (const float*)d_in[29];
    const float* cat_w    = (const float*)d_in[30];
    const float* cat_b    = (const float*)d_in[31];
    const float* lins_w   = (const float*)d_in[32];
    const float* lins_b   = (const float*)d_in[33];
    const float* gn_w     = (const float*)d_in[34];
    const float* gn_b     = (const float*)d_in[35];
    const float* gn_ms    = (const float*)d_in[36];
    const float* fin_w    = (const float*)d_in[37];
    const float* fin_b    = (const float*)d_in[38];

    float* ws = (float*)d_ws;
    size_t NH = (size_t)Nn * Hh;          // 15,360,000 floats
    float* P0    = ws;                    // x / xl
    float* B1    = ws + NH;               // T / agg / h ping
    float* B2    = ws + 2 * NH;           // h2 / h pong
    float* B3    = (float*)d_out;         // h1 scratch (rewritten fully at the end)
    float* gmean = ws + 3 * NH;           // [G, 256]
    float* grstd = gmean + (size_t)Gc * Hh;
    float* colsum = grstd + (size_t)Gc * Hh;   // 256
    float* colsq  = colsum + 256;              // 256
    int*   gstart = (int*)(colsq + 256);       // 2048 ints reserved
    float* Uc    = colsq + 256 + 2048;         // 256B-aligned chunk buffer [CE, 64]

    // adaptive chunk size from remaining workspace
    long avail = (long)(ws_size / sizeof(float)) - (long)(Uc - ws) - 64;
    int CE = (int)(avail / Mm);
    if (CE > Ee) CE = Ee;
    if (CE < 7500) CE = 7500;

    long totNH = (long)Nn * Hh;
    int blksNH = (int)((totNH + 255) / 256);

    embed_x_kernel<<<Nn, 256, 0, stream>>>(x_idx, x_tab, P0);
    seg_bounds_kernel<<<(Gc + 256) / 256, 256, 0, stream>>>(batch, gstart);

    dim3 gN((Nn + 127) / 128, 2);

    for (int l = 0; l < Lc; l++) {
        // T = x @ linx_w + b -> B1 ; xl = relu(BN(T)) -> P0
        gemm_kernel<<<gN, 256, 0, stream>>>(P0, Hh, linx_w + (size_t)l * Hh * Hh,
                                            nullptr, 0, nullptr,
                                            linx_b + l * Hh, nullptr, B1, Hh,
                                            Nn, 256, 256, 0);
        hipMemsetAsync(colsum, 0, 512 * sizeof(float), stream);
        colstats_kernel<<<256, 256, 0, stream>>>(B1, totNH, colsum, colsq);
        bn_relu_kernel<<<blksNH, 256, 0, stream>>>(B1, P0, colsum, colsq,
                                                   linx_g + l * Hh, linx_be + l * Hh,
                                                   1.f / Nn, totNH);

        // ---- two conv branches: h1 -> B3(d_out), h2 -> B2 ----
        for (int br = 0; br < 2; br++) {
            const float* fw1 = br == 0 ? f1_w1 + (size_t)l * F1c * Mm : f2_w1 + (size_t)l * 6 * Mm;
            const float* fb1 = br == 0 ? f1_b1 + l * Mm : f2_b1 + l * Mm;
            const float* fg  = br == 0 ? f1_g + l * Mm  : f2_g + l * Mm;
            const float* fbe = br == 0 ? f1_be + l * Mm : f2_be + l * Mm;
            const float* fw2 = br == 0 ? f1_w2 + (size_t)l * Mm * Hh : f2_w2 + (size_t)l * Mm * Hh;
            const float* fb2 = br == 0 ? f1_b2 + l * Hh : f2_b2 + l * Hh;
            const float* feat = br == 0 ? feature1 : feature2;
            int Kf = br == 0 ? F1c : 6;
            const float* relw  = br == 0 ? c1_rel_w + (size_t)l * Hh * Hh  : c2_rel_w + (size_t)l * Hh * Hh;
            const float* relb  = br == 0 ? c1_rel_b + l * Hh               : c2_rel_b + l * Hh;
            const float* rootw = br == 0 ? c1_root_w + (size_t)l * Hh * Hh : c2_root_w + (size_t)l * Hh * Hh;
            float* hbr = br == 0 ? B3 : B2;

            // BN stats over all E rows of feat@fw1+b (recomputed on the fly)
            hipMemsetAsync(colsum, 0, 512 * sizeof(float), stream);
            feat_stats_kernel<<<256, 256, 0, stream>>>(feat, fw1, fb1, Kf, colsum, colsq);
            // agg = 0
            hipMemsetAsync(B1, 0, NH * sizeof(float), stream);
            // chunked: Uc = relu(BN(...)); edge-weight GEMM fused with scatter
            for (int c0 = 0; c0 < Ee; c0 += CE) {
                int ec = Ee - c0 < CE ? Ee - c0 : CE;
                int blksU = (ec * Mm + 255) / 256;
                feat_bn_kernel<<<blksU, 256, 0, stream>>>(feat, fw1, fb1, Kf, colsum, colsq,
                                                          fg, fbe, 1.f / Ee, Uc, c0, ec);
                dim3 gsc((ec + 127) / 128, 2);
                gemm_scatter_kernel<<<gsc, 256, 0, stream>>>(Uc, fw2, fb2, P0, edge_index,
                                                             B1, c0, ec);
            }
            // h_br = relu(agg @ rel_w + xl @ root_w + rel_b)
            gemm_kernel<<<gN, 256, 0, stream>>>(B1, Hh, relw, P0, Hh, rootw,
                                                relb, nullptr, hbr, Hh,
                                                Nn, 256, 512, 1);
        }

        // h = relu([h1,h2] @ cat_w + cat_b) + xl -> B1
        gemm_kernel<<<gN, 256, 0, stream>>>(B3, Hh, cat_w + (size_t)l * 2 * Hh * Hh,
                                            B2, Hh, cat_w + (size_t)l * 2 * Hh * Hh + Hh * Hh,
                                            cat_b + l * Hh, P0, B1, Hh,
                                            Nn, 256, 512, 1);
        // residual linears: B1 -> B2 -> B1 -> B2
        float* cur = B1; float* oth = B2;
        for (int k = 0; k < NLc; k++) {
            gemm_kernel<<<gN, 256, 0, stream>>>(cur, Hh, lins_w + ((size_t)l * NLc + k) * Hh * Hh,
                                                nullptr, 0, nullptr,
                                                lins_b + ((size_t)l * NLc + k) * Hh, cur,
                                                oth, Hh, Nn, 256, 256, 1);
            float* t = cur; cur = oth; oth = t;
        }
        // cur == B2. GraphNorm: mean -> out(B1) -> rstd -> apply(B1 in place)
        gn_mean_kernel<<<Gc, 256, 0, stream>>>(cur, gstart, gmean);
        gn_out_kernel<<<blksNH, 256, 0, stream>>>(cur, gmean, batch, gn_ms + l * Hh, oth);
        gn_rstd_kernel<<<Gc, 256, 0, stream>>>(oth, gstart, grstd);
        gn_apply_kernel<<<blksNH, 256, 0, stream>>>(oth, grstd, batch, gn_w + l * Hh,
                                                    gn_b + l * Hh);
        // x_next = h @ fin_w + fin_b -> P0 (or d_out on last layer)
        float* xn = (l == Lc - 1) ? (float*)d_out : P0;
        gemm_kernel<<<gN, 256, 0, stream>>>(oth, Hh, fin_w + (size_t)l * Hh * Hh,
                                            nullptr, 0, nullptr, fin_b + l * Hh, nullptr,
                                            xn, Hh, Nn, 256, 256, 0);
    }
}

// Round 3
// 11153.728 us; speedup vs baseline: 1.9586x; 1.9586x over previous
//
#include <hip/hip_runtime.h>
#include <cstdint>

constexpr int Nn = 60000;
constexpr int Ee = 240000;
constexpr int Hh = 256;
constexpr int Mm = 64;
constexpr int F1c = 12;
constexpr int Lc = 4;
constexpr int NLc = 3;
constexpr int Gc = 2000;
constexpr float EPSc = 1e-5f;
constexpr int NB = (Nn + 255) / 256;   // 235 scan blocks

// ---------------- embedding: x[n,c] = sum_j x_tab[x_idx[n,j], c] ----------------
__global__ void embed_x_kernel(const int* __restrict__ xidx, const float* __restrict__ xtab,
                               float* __restrict__ x) {
    int n = blockIdx.x;
    int c = threadIdx.x;
    __shared__ int idx[9];
    if (c < 9) idx[c] = xidx[n * 9 + c];
    __syncthreads();
    float s = 0.f;
#pragma unroll
    for (int j = 0; j < 9; j++) s += xtab[idx[j] * Hh + c];
    x[(size_t)n * Hh + c] = s;
}

// ---------------- graph segment boundaries via binary search (batch sorted) -------
__global__ void seg_bounds_kernel(const int* __restrict__ batch, int* __restrict__ gstart) {
    int g = blockIdx.x * 256 + threadIdx.x;
    if (g > Gc) return;
    if (g == Gc) { gstart[Gc] = Nn; return; }
    int lo = 0, hi = Nn;
    while (lo < hi) { int mid = (lo + hi) >> 1; if (batch[mid] < g) lo = mid + 1; else hi = mid; }
    gstart[g] = lo;
}

// ---------------- CSR build: counting sort of edges by dst ------------------------
__global__ void deg_hist_kernel(const int* __restrict__ ei, int* __restrict__ deg) {
    int e = blockIdx.x * 256 + threadIdx.x;
    if (e >= Ee) return;
    atomicAdd(&deg[ei[Ee + e]], 1);
}

__global__ void psum_block_kernel(const int* __restrict__ deg, int* __restrict__ iscan,
                                  int* __restrict__ bsum) {
    __shared__ int s[256];
    int t = threadIdx.x;
    int i = blockIdx.x * 256 + t;
    int v = (i < Nn) ? deg[i] : 0;
    s[t] = v;
    __syncthreads();
    for (int off = 1; off < 256; off <<= 1) {
        int add = (t >= off) ? s[t - off] : 0;
        __syncthreads();
        s[t] += add;
        __syncthreads();
    }
    if (i < Nn) iscan[i] = s[t];
    if (t == 255) bsum[blockIdx.x] = s[255];
}

__global__ void scan_bsum_kernel(const int* __restrict__ bsum, int* __restrict__ ebase,
                                 int* __restrict__ rowptr) {
    if (threadIdx.x != 0 || blockIdx.x != 0) return;
    int run = 0;
    for (int b = 0; b < NB; b++) { ebase[b] = run; run += bsum[b]; }
    rowptr[Nn] = Ee;
}

__global__ void finalize_rowptr_kernel(const int* __restrict__ deg, const int* __restrict__ iscan,
                                       const int* __restrict__ ebase, int* __restrict__ rowptr) {
    int i = blockIdx.x * 256 + threadIdx.x;
    if (i >= Nn) return;
    rowptr[i] = ebase[i >> 8] + iscan[i] - deg[i];
}

__global__ void fill_eid_kernel(const int* __restrict__ ei, int* __restrict__ cursor,
                                int* __restrict__ eid, int* __restrict__ esrc) {
    int e = blockIdx.x * 256 + threadIdx.x;
    if (e >= Ee) return;
    int dst = ei[Ee + e];
    int pos = atomicAdd(&cursor[dst], 1);
    eid[pos] = e;
    esrc[pos] = ei[e];
}

// ---------------- column sum / sumsq over [rows, 256] (node BatchNorm) ------------
__global__ void colstats_kernel(const float* __restrict__ A, long total,
                                float* __restrict__ sum, float* __restrict__ sq) {
    long i0 = (long)blockIdx.x * blockDim.x + threadIdx.x;
    long stride = (long)gridDim.x * blockDim.x;
    float s = 0.f, q = 0.f;
    for (long i = i0; i < total; i += stride) { float v = A[i]; s += v; q += v * v; }
    int col = (int)(i0 & 255);
    atomicAdd(&sum[col], s);
    atomicAdd(&sq[col], q);
}

// ---------------- BN apply + ReLU over [rows, 256] --------------------------------
__global__ void bn_relu_kernel(const float* __restrict__ A, float* __restrict__ outp,
                               const float* __restrict__ sum, const float* __restrict__ sq,
                               const float* __restrict__ g, const float* __restrict__ be,
                               float rinv, long total) {
    long i = (long)blockIdx.x * 256 + threadIdx.x;
    if (i >= total) return;
    int col = (int)(i & 255);
    float m = sum[col] * rinv;
    float var = sq[col] * rinv - m * m;
    float v = (A[i] - m) * rsqrtf(var + EPSc) * g[col] + be[col];
    outp[i] = fmaxf(v, 0.f);
}

// ------- edge-feature stats: recompute U = feat@W1 + b on the fly, accumulate -----
__global__ void feat_stats_kernel(const float* __restrict__ F, const float* __restrict__ W,
                                  const float* __restrict__ b, int K,
                                  float* __restrict__ sum, float* __restrict__ sq) {
    __shared__ float Wsh[F1c * Mm];
    __shared__ float bsh[Mm];
    int tid = threadIdx.x;
    for (int i = tid; i < K * Mm; i += 256) Wsh[i] = W[i];
    if (tid < Mm) bsh[tid] = b[tid];
    __syncthreads();
    long total = (long)Ee * Mm;
    long i0 = (long)blockIdx.x * 256 + tid;
    long stride = (long)gridDim.x * 256;
    float s = 0.f, q = 0.f;
    for (long i = i0; i < total; i += stride) {
        int r = (int)(i >> 6), m = (int)(i & 63);
        const float* fr = F + (size_t)r * K;
        float u = bsh[m];
        for (int k = 0; k < K; k++) u += fr[k] * Wsh[k * Mm + m];
        s += u; q += u * u;
    }
    int m0 = (int)(i0 & 63);
    atomicAdd(&sum[m0], s);
    atomicAdd(&sq[m0], q);
}

// ------- per-chunk (dst-sorted order): Uc[i] = relu(BN(feat[eid[c0+i]]@W1 + b)) ----
__global__ void feat_bn_kernel(const float* __restrict__ F, const float* __restrict__ W,
                               const float* __restrict__ b, int K,
                               const float* __restrict__ sum, const float* __restrict__ sq,
                               const float* __restrict__ g, const float* __restrict__ be,
                               float rinv, const int* __restrict__ eid,
                               float* __restrict__ Uc, int c0, int ec) {
    __shared__ float Wsh[F1c * Mm];
    __shared__ float bsh[Mm];
    int tid = threadIdx.x;
    for (int i = tid; i < K * Mm; i += 256) Wsh[i] = W[i];
    if (tid < Mm) bsh[tid] = b[tid];
    __syncthreads();
    int i = blockIdx.x * 256 + tid;
    if (i >= ec * Mm) return;
    int rl = i >> 6, m = i & 63;
    const float* fr = F + (size_t)eid[c0 + rl] * K;
    float u = bsh[m];
    for (int k = 0; k < K; k++) u += fr[k] * Wsh[k * Mm + m];
    float mu = sum[m] * rinv;
    float var = sq[m] * rinv - mu * mu;
    float v = (u - mu) * rsqrtf(var + EPSc) * g[m] + be[m];
    Uc[i] = fmaxf(v, 0.f);
}

// ---------------- main SGEMM: C = act(A1@W1 [+ A2@W2] + bias) [+ res] -------------
__global__ __launch_bounds__(256) void gemm_kernel(
    const float* __restrict__ A1, int lda1, const float* __restrict__ W1,
    const float* __restrict__ A2, int lda2, const float* __restrict__ W2,
    const float* __restrict__ bias, const float* __restrict__ res,
    float* __restrict__ C, int ldc,
    int rows, int K1, int Ktot, int do_relu) {
    __shared__ float As[16][128];
    __shared__ float Ws[16][128];
    int tid = threadIdx.x;
    int tx = tid & 15;
    int ty = tid >> 4;
    int r0 = blockIdx.x * 128;
    int j0 = blockIdx.y * 128;

    float acc[8][8];
#pragma unroll
    for (int i = 0; i < 8; i++)
#pragma unroll
        for (int j = 0; j < 8; j++) acc[i][j] = 0.f;

    int arow = tid >> 1;
    int ak = (tid & 1) * 8;
    int wcol = tid & 127;
    int wkb = (tid >> 7) * 8;

    for (int kt = 0; kt < Ktot; kt += 16) {
        const float* A; int lda; int koff;
        if (kt < K1) { A = A1; lda = lda1; koff = kt; }
        else         { A = A2; lda = lda2; koff = kt - K1; }
        int grow = r0 + arow;
        float4 av0 = make_float4(0.f, 0.f, 0.f, 0.f);
        float4 av1 = make_float4(0.f, 0.f, 0.f, 0.f);
        if (grow < rows) {
            const float* ap = A + (size_t)grow * lda + koff + ak;
            av0 = *(const float4*)ap;
            av1 = *(const float4*)(ap + 4);
        }
        As[ak + 0][arow] = av0.x; As[ak + 1][arow] = av0.y;
        As[ak + 2][arow] = av0.z; As[ak + 3][arow] = av0.w;
        As[ak + 4][arow] = av1.x; As[ak + 5][arow] = av1.y;
        As[ak + 6][arow] = av1.z; As[ak + 7][arow] = av1.w;

        const float* W; int wkoff;
        if (kt < K1) { W = W1; wkoff = kt; }
        else         { W = W2; wkoff = kt - K1; }
#pragma unroll
        for (int i = 0; i < 8; i++) {
            int kk = wkb + i;
            Ws[kk][wcol] = W[(size_t)(wkoff + kk) * 256 + j0 + wcol];
        }
        __syncthreads();

#pragma unroll
        for (int kk = 0; kk < 16; kk++) {
            float ar[8], br[8];
            *(float4*)&ar[0] = *(const float4*)&As[kk][ty * 8];
            *(float4*)&ar[4] = *(const float4*)&As[kk][ty * 8 + 4];
            *(float4*)&br[0] = *(const float4*)&Ws[kk][tx * 8];
            *(float4*)&br[4] = *(const float4*)&Ws[kk][tx * 8 + 4];
#pragma unroll
            for (int i = 0; i < 8; i++)
#pragma unroll
                for (int j = 0; j < 8; j++) acc[i][j] += ar[i] * br[j];
        }
        __syncthreads();
    }

#pragma unroll
    for (int i = 0; i < 8; i++) {
        int r = r0 + ty * 8 + i;
        if (r >= rows) continue;
#pragma unroll
        for (int j = 0; j < 8; j++) {
            int c = j0 + tx * 8 + j;
            float v = acc[i][j] + bias[c];
            if (do_relu) v = fmaxf(v, 0.f);
            if (res) v += res[(size_t)r * 256 + c];
            C[(size_t)r * ldc + c] = v;
        }
    }
}

// ------- gather-aggregate: agg[n,:] += sum over CSR edges i in [c0,c1) owned by n:
//         Wc[i-c0,:] * xl[esrc[i],:]       (one wave per node, no atomics)
__global__ __launch_bounds__(256) void gather_agg_kernel(
    const int* __restrict__ rowptr, const int* __restrict__ esrc,
    const float* __restrict__ Wc, const float* __restrict__ xl,
    float* __restrict__ agg, int c0, int c1) {
    int n = (blockIdx.x * 256 + threadIdx.x) >> 6;
    if (n >= Nn) return;
    int lane = threadIdx.x & 63;
    int rs = rowptr[n], re = rowptr[n + 1];
    if (rs < c0) rs = c0;
    if (re > c1) re = c1;
    if (rs >= re) return;
    float* ap = agg + (size_t)n * Hh + lane * 4;
    float4 acc = *(float4*)ap;
    for (int i = rs; i < re; i++) {
        float4 wv = *(const float4*)(Wc + (size_t)(i - c0) * Hh + lane * 4);
        float4 xv = *(const float4*)(xl + (size_t)esrc[i] * Hh + lane * 4);
        acc.x += wv.x * xv.x; acc.y += wv.y * xv.y;
        acc.z += wv.z * xv.z; acc.w += wv.w * xv.w;
    }
    *(float4*)ap = acc;
}

// ---------------- GraphNorm ----------------
__global__ void gn_mean_kernel(const float* __restrict__ h, const int* __restrict__ gstart,
                               float* __restrict__ mean) {
    int g = blockIdx.x, c = threadIdx.x;
    int s = gstart[g], e = gstart[g + 1];
    float acc = 0.f;
    for (int n = s; n < e; n++) acc += h[(size_t)n * Hh + c];
    float cnt = (float)((e - s) > 1 ? (e - s) : 1);
    mean[(size_t)g * Hh + c] = acc / cnt;
}

__global__ void gn_out_kernel(const float* __restrict__ h, const float* __restrict__ mean,
                              const int* __restrict__ batch, const float* __restrict__ ms,
                              float* __restrict__ outp) {
    long i = (long)blockIdx.x * 256 + threadIdx.x;
    if (i >= (long)Nn * Hh) return;
    int n = (int)(i >> 8);
    int c = (int)(i & 255);
    outp[i] = h[i] - ms[c] * mean[(size_t)batch[n] * Hh + c];
}

__global__ void gn_rstd_kernel(const float* __restrict__ outp, const int* __restrict__ gstart,
                               float* __restrict__ rstd) {
    int g = blockIdx.x, c = threadIdx.x;
    int s = gstart[g], e = gstart[g + 1];
    float acc = 0.f;
    for (int n = s; n < e; n++) { float v = outp[(size_t)n * Hh + c]; acc += v * v; }
    float cnt = (float)((e - s) > 1 ? (e - s) : 1);
    rstd[(size_t)g * Hh + c] = rsqrtf(acc / cnt + EPSc);
}

__global__ void gn_apply_kernel(float* __restrict__ outp, const float* __restrict__ rstd,
                                const int* __restrict__ batch, const float* __restrict__ w,
                                const float* __restrict__ b) {
    long i = (long)blockIdx.x * 256 + threadIdx.x;
    if (i >= (long)Nn * Hh) return;
    int n = (int)(i >> 8);
    int c = (int)(i & 255);
    outp[i] = outp[i] * rstd[(size_t)batch[n] * Hh + c] * w[c] + b[c];
}

// =====================================================================================
extern "C" void kernel_launch(void* const* d_in, const int* in_sizes, int n_in,
                              void* d_out, int out_size, void* d_ws, size_t ws_size,
                              hipStream_t stream) {
    const int* x_idx      = (const int*)d_in[0];
    const int* edge_index = (const int*)d_in[2];
    const int* batch      = (const int*)d_in[3];
    const float* feature1 = (const float*)d_in[4];
    const float* feature2 = (const float*)d_in[5];
    const float* x_tab    = (const float*)d_in[6];
    const float* linx_w   = (const float*)d_in[8];
    const float* linx_b   = (const float*)d_in[9];
    const float* linx_g   = (const float*)d_in[10];
    const float* linx_be  = (const float*)d_in[11];
    const float* f1_w1    = (const float*)d_in[12];
    const float* f1_b1    = (const float*)d_in[13];
    const float* f1_g     = (const float*)d_in[14];
    const float* f1_be    = (const float*)d_in[15];
    const float* f1_w2    = (const float*)d_in[16];
    const float* f1_b2    = (const float*)d_in[17];
    const float* f2_w1    = (const float*)d_in[18];
    const float* f2_b1    = (const float*)d_in[19];
    const float* f2_g     = (const float*)d_in[20];
    const float* f2_be    = (const float*)d_in[21];
    const float* f2_w2    = (const float*)d_in[22];
    const float* f2_b2    = (const float*)d_in[23];
    const float* c1_rel_w  = (const float*)d_in[24];
    const float* c1_rel_b  = (const float*)d_in[25];
    const float* c1_root_w = (const float*)d_in[26];
    const float* c2_rel_w  = (const float*)d_in[27];
    const float* c2_rel_b  = (const float*)d_in[28];
    const float* c2_root_w = (const float*)d_in[29];
    const float* cat_w    = (const float*)d_in[30];
    const float* cat_b    = (const float*)d_in[31];
    const float* lins_w   = (const float*)d_in[32];
    const float* lins_b   = (const float*)d_in[33];
    const float* gn_w     = (const float*)d_in[34];
    const float* gn_b     = (const float*)d_in[35];
    const float* gn_ms    = (const float*)d_in[36];
    const float* fin_w    = (const float*)d_in[37];
    const float* fin_b    = (const float*)d_in[38];

    float* ws = (float*)d_ws;
    size_t NH = (size_t)Nn * Hh;
    float* P0    = ws;                    // x / xl
    float* B1    = ws + NH;               // T / agg / h ping
    float* B2    = ws + 2 * NH;           // h2 / h pong
    float* B3    = (float*)d_out;         // h1 scratch (fully rewritten at the end)
    float* gmean = ws + 3 * NH;
    float* grstd = gmean + (size_t)Gc * Hh;
    float* colsum = grstd + (size_t)Gc * Hh;   // 256
    float* colsq  = colsum + 256;              // 256
    int*   ibase  = (int*)(colsq + 256);
    int*   gstart = ibase;                     // 2048 ints
    int*   deg    = ibase + 2048;              // N
    int*   iscan  = deg + Nn;                  // N
    int*   rowptr = iscan + Nn;                // N+1 (reserve N+256)
    int*   cursor = rowptr + Nn + 256;         // N
    int*   bsum   = cursor + Nn;               // 256
    int*   ebase  = bsum + 256;                // 256
    int*   eid    = ebase + 256;               // E
    int*   esrc   = eid + Ee;                  // E
    // align Uc to 256 floats
    size_t ioff = (size_t)((esrc + Ee) - ibase);
    size_t ustart = ((size_t)(ibase - (int*)ws) + ioff + 255) & ~(size_t)255;
    float* Uc = ws + ustart;

    long avail = (long)(ws_size / sizeof(float)) - (long)ustart - 256;
    int CE = (int)(avail / (Mm + Hh));          // Uc row (64) + Wc row (256)
    if (CE > Ee) CE = Ee;
    if (CE < 4800) CE = 4800;
    float* Wc = Uc + (size_t)CE * Mm;

    long totNH = (long)Nn * Hh;
    int blksNH = (int)((totNH + 255) / 256);
    int blksE  = (Ee + 255) / 256;
    int blksN  = (Nn + 255) / 256;

    embed_x_kernel<<<Nn, 256, 0, stream>>>(x_idx, x_tab, P0);
    seg_bounds_kernel<<<(Gc + 256) / 256, 256, 0, stream>>>(batch, gstart);

    // ---- build dst-sorted CSR once ----
    hipMemsetAsync(deg, 0, Nn * sizeof(int), stream);
    deg_hist_kernel<<<blksE, 256, 0, stream>>>(edge_index, deg);
    psum_block_kernel<<<NB, 256, 0, stream>>>(deg, iscan, bsum);
    scan_bsum_kernel<<<1, 64, 0, stream>>>(bsum, ebase, rowptr);
    finalize_rowptr_kernel<<<blksN, 256, 0, stream>>>(deg, iscan, ebase, rowptr);
    hipMemcpyAsync(cursor, rowptr, Nn * sizeof(int), hipMemcpyDeviceToDevice, stream);
    fill_eid_kernel<<<blksE, 256, 0, stream>>>(edge_index, cursor, eid, esrc);

    dim3 gN((Nn + 127) / 128, 2);

    for (int l = 0; l < Lc; l++) {
        // T = x @ linx_w + b -> B1 ; xl = relu(BN(T)) -> P0
        gemm_kernel<<<gN, 256, 0, stream>>>(P0, Hh, linx_w + (size_t)l * Hh * Hh,
                                            nullptr, 0, nullptr,
                                            linx_b + l * Hh, nullptr, B1, Hh,
                                            Nn, 256, 256, 0);
        hipMemsetAsync(colsum, 0, 512 * sizeof(float), stream);
        colstats_kernel<<<256, 256, 0, stream>>>(B1, totNH, colsum, colsq);
        bn_relu_kernel<<<blksNH, 256, 0, stream>>>(B1, P0, colsum, colsq,
                                                   linx_g + l * Hh, linx_be + l * Hh,
                                                   1.f / Nn, totNH);

        // ---- two conv branches: h1 -> B3(d_out), h2 -> B2 ----
        for (int br = 0; br < 2; br++) {
            const float* fw1 = br == 0 ? f1_w1 + (size_t)l * F1c * Mm : f2_w1 + (size_t)l * 6 * Mm;
            const float* fb1 = br == 0 ? f1_b1 + l * Mm : f2_b1 + l * Mm;
            const float* fg  = br == 0 ? f1_g + l * Mm  : f2_g + l * Mm;
            const float* fbe = br == 0 ? f1_be + l * Mm : f2_be + l * Mm;
            const float* fw2 = br == 0 ? f1_w2 + (size_t)l * Mm * Hh : f2_w2 + (size_t)l * Mm * Hh;
            const float* fb2 = br == 0 ? f1_b2 + l * Hh : f2_b2 + l * Hh;
            const float* feat = br == 0 ? feature1 : feature2;
            int Kf = br == 0 ? F1c : 6;
            const float* relw  = br == 0 ? c1_rel_w + (size_t)l * Hh * Hh  : c2_rel_w + (size_t)l * Hh * Hh;
            const float* relb  = br == 0 ? c1_rel_b + l * Hh               : c2_rel_b + l * Hh;
            const float* rootw = br == 0 ? c1_root_w + (size_t)l * Hh * Hh : c2_root_w + (size_t)l * Hh * Hh;
            float* hbr = br == 0 ? B3 : B2;

            // BN stats over all E rows of feat@fw1+b (recomputed on the fly)
            hipMemsetAsync(colsum, 0, 512 * sizeof(float), stream);
            feat_stats_kernel<<<256, 256, 0, stream>>>(feat, fw1, fb1, Kf, colsum, colsq);
            // agg = 0
            hipMemsetAsync(B1, 0, NH * sizeof(float), stream);
            // chunked (dst-sorted): Uc -> Wc GEMM -> gather aggregate (no atomics)
            for (int c0 = 0; c0 < Ee; c0 += CE) {
                int ec = Ee - c0 < CE ? Ee - c0 : CE;
                int blksU = (ec * Mm + 255) / 256;
                feat_bn_kernel<<<blksU, 256, 0, stream>>>(feat, fw1, fb1, Kf, colsum, colsq,
                                                          fg, fbe, 1.f / Ee, eid, Uc, c0, ec);
                dim3 gc((ec + 127) / 128, 2);
                gemm_kernel<<<gc, 256, 0, stream>>>(Uc, Mm, fw2, nullptr, 0, nullptr,
                                                    fb2, nullptr, Wc, Hh, ec, 64, 64, 1);
                gather_agg_kernel<<<(Nn * 64 + 255) / 256, 256, 0, stream>>>(
                    rowptr, esrc, Wc, P0, B1, c0, c0 + ec);
            }
            // h_br = relu(agg @ rel_w + xl @ root_w + rel_b)
            gemm_kernel<<<gN, 256, 0, stream>>>(B1, Hh, relw, P0, Hh, rootw,
                                                relb, nullptr, hbr, Hh,
                                                Nn, 256, 512, 1);
        }

        // h = relu([h1,h2] @ cat_w + cat_b) + xl -> B1
        gemm_kernel<<<gN, 256, 0, stream>>>(B3, Hh, cat_w + (size_t)l * 2 * Hh * Hh,
                                            B2, Hh, cat_w + (size_t)l * 2 * Hh * Hh + Hh * Hh,
                                            cat_b + l * Hh, P0, B1, Hh,
                                            Nn, 256, 512, 1);
        // residual linears: B1 -> B2 -> B1 -> B2
        float* cur = B1; float* oth = B2;
        for (int k = 0; k < NLc; k++) {
            gemm_kernel<<<gN, 256, 0, stream>>>(cur, Hh, lins_w + ((size_t)l * NLc + k) * Hh * Hh,
                                                nullptr, 0, nullptr,
                                                lins_b + ((size_t)l * NLc + k) * Hh, cur,
                                                oth, Hh, Nn, 256, 256, 1);
            float* t = cur; cur = oth; oth = t;
        }
        // cur == B2. GraphNorm: mean -> out(B1) -> rstd -> apply in place
        gn_mean_kernel<<<Gc, 256, 0, stream>>>(cur, gstart, gmean);
        gn_out_kernel<<<blksNH, 256, 0, stream>>>(cur, gmean, batch, gn_ms + l * Hh, oth);
        gn_rstd_kernel<<<Gc, 256, 0, stream>>>(oth, gstart, grstd);
        gn_apply_kernel<<<blksNH, 256, 0, stream>>>(oth, grstd, batch, gn_w + l * Hh,
                                                    gn_b + l * Hh);
        // x_next = h @ fin_w + fin_b -> P0 (or d_out on last layer)
        float* xn = (l == Lc - 1) ? (float*)d_out : P0;
        gemm_kernel<<<gN, 256, 0, stream>>>(oth, Hh, fin_w + (size_t)l * Hh * Hh,
                                            nullptr, 0, nullptr, fin_b + l * Hh, nullptr,
                                            xn, Hh, Nn, 256, 256, 0);
    }
}

// Round 5
// 9076.907 us; speedup vs baseline: 2.4067x; 1.2288x over previous
//
#include <hip/hip_runtime.h>
#include <cstdint>

constexpr int Nn = 60000;
constexpr int Ee = 240000;
constexpr int Hh = 256;
constexpr int Mm = 64;
constexpr int F1c = 12;
constexpr int Lc = 4;
constexpr int NLc = 3;
constexpr int Gc = 2000;
constexpr float EPSc = 1e-5f;
constexpr int NB = (Nn + 255) / 256;

typedef __attribute__((ext_vector_type(8))) short bf16x8;
typedef __attribute__((ext_vector_type(4))) short s16x4;
typedef __attribute__((ext_vector_type(4))) float f32x4;
typedef __attribute__((ext_vector_type(4))) unsigned short u16x4;
typedef unsigned short ushortt;

__device__ __forceinline__ float bf2f(ushortt u) {
    union { unsigned int i; float f; } c; c.i = ((unsigned int)u) << 16; return c.f;
}
__device__ __forceinline__ ushortt f2bf(float f) {
    union { float f; unsigned int i; } c; c.f = f;
    unsigned int u = c.i;
    return (ushortt)((u + 0x7FFFu + ((u >> 16) & 1u)) >> 16);
}

// ---------------- embedding (fp32) ----------------
__global__ void embed_x_kernel(const int* __restrict__ xidx, const float* __restrict__ xtab,
                               float* __restrict__ x) {
    int n = blockIdx.x;
    int c = threadIdx.x;
    __shared__ int idx[9];
    if (c < 9) idx[c] = xidx[n * 9 + c];
    __syncthreads();
    float s = 0.f;
#pragma unroll
    for (int j = 0; j < 9; j++) s += xtab[idx[j] * Hh + c];
    x[(size_t)n * Hh + c] = s;
}

__global__ void seg_bounds_kernel(const int* __restrict__ batch, int* __restrict__ gstart) {
    int g = blockIdx.x * 256 + threadIdx.x;
    if (g > Gc) return;
    if (g == Gc) { gstart[Gc] = Nn; return; }
    int lo = 0, hi = Nn;
    while (lo < hi) { int mid = (lo + hi) >> 1; if (batch[mid] < g) lo = mid + 1; else hi = mid; }
    gstart[g] = lo;
}

// ---------------- CSR build ----------------
__global__ void deg_hist_kernel(const int* __restrict__ ei, int* __restrict__ deg) {
    int e = blockIdx.x * 256 + threadIdx.x;
    if (e >= Ee) return;
    atomicAdd(&deg[ei[Ee + e]], 1);
}

__global__ void psum_block_kernel(const int* __restrict__ deg, int* __restrict__ iscan,
                                  int* __restrict__ bsum) {
    __shared__ int s[256];
    int t = threadIdx.x;
    int i = blockIdx.x * 256 + t;
    int v = (i < Nn) ? deg[i] : 0;
    s[t] = v;
    __syncthreads();
    for (int off = 1; off < 256; off <<= 1) {
        int add = (t >= off) ? s[t - off] : 0;
        __syncthreads();
        s[t] += add;
        __syncthreads();
    }
    if (i < Nn) iscan[i] = s[t];
    if (t == 255) bsum[blockIdx.x] = s[255];
}

__global__ void scan_bsum_kernel(const int* __restrict__ bsum, int* __restrict__ ebase,
                                 int* __restrict__ rowptr) {
    if (threadIdx.x != 0 || blockIdx.x != 0) return;
    int run = 0;
    for (int b = 0; b < NB; b++) { ebase[b] = run; run += bsum[b]; }
    rowptr[Nn] = Ee;
}

__global__ void finalize_rowptr_kernel(const int* __restrict__ deg, const int* __restrict__ iscan,
                                       const int* __restrict__ ebase, int* __restrict__ rowptr) {
    int i = blockIdx.x * 256 + threadIdx.x;
    if (i >= Nn) return;
    rowptr[i] = ebase[i >> 8] + iscan[i] - deg[i];
}

__global__ void fill_eid_kernel(const int* __restrict__ ei, int* __restrict__ cursor,
                                int* __restrict__ eid, int* __restrict__ esrc) {
    int e = blockIdx.x * 256 + threadIdx.x;
    if (e >= Ee) return;
    int dst = ei[Ee + e];
    int pos = atomicAdd(&cursor[dst], 1);
    eid[pos] = e;
    esrc[pos] = ei[e];
}

// ------- weight transpose + hi/lo bf16 split -------------------------------------
// w = src[m*srcMS + k*256 + c]; dstHi/Lo[m*dstMS + c*dstLD + kOff + k]
__global__ void wconv_kernel(const float* __restrict__ src, ushortt* __restrict__ dstHi,
                             ushortt* __restrict__ dstLo,
                             int nmat, int K, int dstLD, long dstMS, int kOff, long srcMS) {
    long idx = (long)blockIdx.x * 256 + threadIdx.x;
    long tot = (long)nmat * 256 * K;
    if (idx >= tot) return;
    int k = (int)(idx % K);
    long t = idx / K;
    int c = (int)(t & 255);
    int m = (int)(t >> 8);
    float w = src[m * srcMS + (long)k * 256 + c];
    ushortt h = f2bf(w);
    long o = m * dstMS + (long)c * dstLD + kOff + k;
    dstHi[o] = h;
    dstLo[o] = f2bf(w - bf2f(h));
}

// ---------------- column stats over fp32 [rows, 256] ------------------------------
__global__ void colstats_kernel(const float* __restrict__ A, long total,
                                float* __restrict__ sum, float* __restrict__ sq) {
    long i0 = (long)blockIdx.x * blockDim.x + threadIdx.x;
    long stride = (long)gridDim.x * blockDim.x;
    float s = 0.f, q = 0.f;
    for (long i = i0; i < total; i += stride) { float v = A[i]; s += v; q += v * v; }
    int col = (int)(i0 & 255);
    atomicAdd(&sum[col], s);
    atomicAdd(&sq[col], q);
}

__global__ void bn_relu_kernel(const float* __restrict__ A, float* __restrict__ outp,
                               const float* __restrict__ sum, const float* __restrict__ sq,
                               const float* __restrict__ g, const float* __restrict__ be,
                               float rinv, long total) {
    long i = (long)blockIdx.x * 256 + threadIdx.x;
    if (i >= total) return;
    int col = (int)(i & 255);
    float m = sum[col] * rinv;
    float var = sq[col] * rinv - m * m;
    float v = (A[i] - m) * rsqrtf(var + EPSc) * g[col] + be[col];
    outp[i] = fmaxf(v, 0.f);
}

// ------- edge-feature stats (fp32 recompute on the fly) ---------------------------
__global__ void feat_stats_kernel(const float* __restrict__ F, const float* __restrict__ W,
                                  const float* __restrict__ b, int K,
                                  float* __restrict__ sum, float* __restrict__ sq) {
    __shared__ float Wsh[F1c * Mm];
    __shared__ float bsh[Mm];
    int tid = threadIdx.x;
    for (int i = tid; i < K * Mm; i += 256) Wsh[i] = W[i];
    if (tid < Mm) bsh[tid] = b[tid];
    __syncthreads();
    long total = (long)Ee * Mm;
    long i0 = (long)blockIdx.x * 256 + tid;
    long stride = (long)gridDim.x * 256;
    float s = 0.f, q = 0.f;
    for (long i = i0; i < total; i += stride) {
        int r = (int)(i >> 6), m = (int)(i & 63);
        const float* fr = F + (size_t)r * K;
        float u = bsh[m];
        for (int k = 0; k < K; k++) u += fr[k] * Wsh[k * Mm + m];
        s += u; q += u * u;
    }
    int m0 = (int)(i0 & 63);
    atomicAdd(&sum[m0], s);
    atomicAdd(&sq[m0], q);
}

// ------- per-chunk dst-sorted: Uc = relu(BN(feat[eid]@W1+b)) fp32 ------------------
__global__ void feat_bn_kernel(const float* __restrict__ F, const float* __restrict__ W,
                               const float* __restrict__ b, int K,
                               const float* __restrict__ sum, const float* __restrict__ sq,
                               const float* __restrict__ g, const float* __restrict__ be,
                               float rinv, const int* __restrict__ eid,
                               float* __restrict__ Uc, int c0, int ec) {
    __shared__ float Wsh[F1c * Mm];
    __shared__ float bsh[Mm];
    int tid = threadIdx.x;
    for (int i = tid; i < K * Mm; i += 256) Wsh[i] = W[i];
    if (tid < Mm) bsh[tid] = b[tid];
    __syncthreads();
    int i = blockIdx.x * 256 + tid;
    if (i >= ec * Mm) return;
    int rl = i >> 6, m = i & 63;
    const float* fr = F + (size_t)eid[c0 + rl] * K;
    float u = bsh[m];
    for (int k = 0; k < K; k++) u += fr[k] * Wsh[k * Mm + m];
    float mu = sum[m] * rinv;
    float var = sq[m] * rinv - mu * mu;
    float v = (u - mu) * rsqrtf(var + EPSc) * g[m] + be[m];
    Uc[i] = fmaxf(v, 0.f);
}

// ---------------- split-bf16 (hi/lo 3-term) MFMA GEMM -----------------------------
// C[rows x 256] fp32 = act(A[rows x Ktot] @ W + bias) (+res). A fp32 split A1/A2 at K1.
// Whi/Wlo: [256][Ktot] bf16 (row = output col). 128x128 tile, 4 waves of 64x64.
__global__ __launch_bounds__(256) void bgemm_kernel(
    const float* __restrict__ A1, int lda1, const float* __restrict__ A2, int lda2,
    const ushortt* __restrict__ Whi, const ushortt* __restrict__ Wlo,
    const float* __restrict__ bias, const float* __restrict__ res,
    float* __restrict__ C, int rows, int K1, int Ktot, int do_relu) {
    __shared__ char lds[65536];
    char* Ah = lds;
    char* Al = lds + 16384;
    char* Wh = lds + 32768;
    char* Wl = lds + 49152;
    int tid = threadIdx.x;
    int lane = tid & 63;
    int wave = tid >> 6;
    int wrow0 = (wave >> 1) * 64;
    int wcol0 = (wave & 1) * 64;
    int r0 = blockIdx.x * 128;
    int j0 = blockIdx.y * 128;
    int l15 = lane & 15;
    int l4 = lane >> 4;

    f32x4 acc[4][4];
#pragma unroll
    for (int i = 0; i < 4; i++)
#pragma unroll
        for (int j = 0; j < 4; j++) acc[i][j] = (f32x4){0.f, 0.f, 0.f, 0.f};

    for (int kt = 0; kt < Ktot; kt += 64) {
        const float* A; int lda; int koff;
        if (kt < K1) { A = A1; lda = lda1; koff = kt; }
        else         { A = A2; lda = lda2; koff = kt - K1; }
        // stage A tile [128 rows][64 k] fp32 -> hi/lo bf16 LDS (swizzled)
#pragma unroll
        for (int p = 0; p < 8; p++) {
            int fid = p * 256 + tid;        // 2048 float4 total
            int row = fid >> 4;             // 16 float4 per row
            int k4 = (fid & 15) * 4;
            int rg = r0 + row; if (rg >= rows) rg = rows - 1;
            float4 v = *(const float4*)(A + (size_t)rg * lda + koff + k4);
            u16x4 hi, lo;
            hi[0] = f2bf(v.x); lo[0] = f2bf(v.x - bf2f(hi[0]));
            hi[1] = f2bf(v.y); lo[1] = f2bf(v.y - bf2f(hi[1]));
            hi[2] = f2bf(v.z); lo[2] = f2bf(v.z - bf2f(hi[2]));
            hi[3] = f2bf(v.w); lo[3] = f2bf(v.w - bf2f(hi[3]));
            int off = (row * 128 + k4 * 2) ^ ((row & 7) << 4);
            *(u16x4*)(Ah + off) = hi;
            *(u16x4*)(Al + off) = lo;
        }
        // stage W hi/lo tiles [128 cols][64 k]
#pragma unroll
        for (int p = 0; p < 4; p++) {
            int b = p * 4096 + tid * 16;
            int row = b >> 7;
            int kb = b & 127;
            uint4 vh = *(const uint4*)((const char*)Whi + ((size_t)(j0 + row) * Ktot + kt) * 2 + kb);
            uint4 vl = *(const uint4*)((const char*)Wlo + ((size_t)(j0 + row) * Ktot + kt) * 2 + kb);
            int off = (row * 128 + kb) ^ ((row & 7) << 4);
            *(uint4*)(Wh + off) = vh;
            *(uint4*)(Wl + off) = vl;
        }
        __syncthreads();
#pragma unroll
        for (int kk = 0; kk < 64; kk += 32) {
            int kbase = (kk + l4 * 4) * 2;
            bf16x8 ah[4], al[4], bh[4], bl[4];
#pragma unroll
            for (int i = 0; i < 4; i++) {
                int row = wrow0 + i * 16 + l15;
                int sw = (row & 7) << 4;
                int o0 = (row * 128 + kbase) ^ sw;
                int o1 = (row * 128 + kbase + 32) ^ sw;
                s16x4 hlo = *(const s16x4*)(Ah + o0);
                s16x4 hhi = *(const s16x4*)(Ah + o1);
                s16x4 llo = *(const s16x4*)(Al + o0);
                s16x4 lhi = *(const s16x4*)(Al + o1);
                bf16x8 fh, fl;
                fh[0] = hlo[0]; fh[1] = hlo[1]; fh[2] = hlo[2]; fh[3] = hlo[3];
                fh[4] = hhi[0]; fh[5] = hhi[1]; fh[6] = hhi[2]; fh[7] = hhi[3];
                fl[0] = llo[0]; fl[1] = llo[1]; fl[2] = llo[2]; fl[3] = llo[3];
                fl[4] = lhi[0]; fl[5] = lhi[1]; fl[6] = lhi[2]; fl[7] = lhi[3];
                ah[i] = fh; al[i] = fl;
            }
#pragma unroll
            for (int j = 0; j < 4; j++) {
                int row = wcol0 + j * 16 + l15;
                int sw = (row & 7) << 4;
                int o0 = (row * 128 + kbase) ^ sw;
                int o1 = (row * 128 + kbase + 32) ^ sw;
                s16x4 hlo = *(const s16x4*)(Wh + o0);
                s16x4 hhi = *(const s16x4*)(Wh + o1);
                s16x4 llo = *(const s16x4*)(Wl + o0);
                s16x4 lhi = *(const s16x4*)(Wl + o1);
                bf16x8 fh, fl;
                fh[0] = hlo[0]; fh[1] = hlo[1]; fh[2] = hlo[2]; fh[3] = hlo[3];
                fh[4] = hhi[0]; fh[5] = hhi[1]; fh[6] = hhi[2]; fh[7] = hhi[3];
                fl[0] = llo[0]; fl[1] = llo[1]; fl[2] = llo[2]; fl[3] = llo[3];
                fl[4] = lhi[0]; fl[5] = lhi[1]; fl[6] = lhi[2]; fl[7] = lhi[3];
                bh[j] = fh; bl[j] = fl;
            }
#pragma unroll
            for (int i = 0; i < 4; i++)
#pragma unroll
                for (int j = 0; j < 4; j++) {
                    acc[i][j] = __builtin_amdgcn_mfma_f32_16x16x32_bf16(ah[i], bh[j], acc[i][j], 0, 0, 0);
                    acc[i][j] = __builtin_amdgcn_mfma_f32_16x16x32_bf16(ah[i], bl[j], acc[i][j], 0, 0, 0);
                    acc[i][j] = __builtin_amdgcn_mfma_f32_16x16x32_bf16(al[i], bh[j], acc[i][j], 0, 0, 0);
                }
        }
        __syncthreads();
    }

#pragma unroll
    for (int i = 0; i < 4; i++) {
#pragma unroll
        for (int r = 0; r < 4; r++) {
            int row = r0 + wrow0 + i * 16 + l4 * 4 + r;
            if (row >= rows) continue;
#pragma unroll
            for (int j = 0; j < 4; j++) {
                int col = j0 + wcol0 + j * 16 + l15;
                float v = acc[i][j][r] + bias[col];
                if (do_relu) v = fmaxf(v, 0.f);
                if (res) v += res[(size_t)row * 256 + col];
                C[(size_t)row * 256 + col] = v;
            }
        }
    }
}

// ------- gather-aggregate (fp32, no atomics) ---------------------------------------
__global__ __launch_bounds__(256) void gather_agg_kernel(
    const int* __restrict__ rowptr, const int* __restrict__ esrc,
    const float* __restrict__ Wc, const float* __restrict__ xl,
    float* __restrict__ agg, int c0, int c1) {
    int n = (blockIdx.x * 256 + threadIdx.x) >> 6;
    if (n >= Nn) return;
    int lane = threadIdx.x & 63;
    int rs = rowptr[n], re = rowptr[n + 1];
    if (rs < c0) rs = c0;
    if (re > c1) re = c1;
    if (rs >= re) return;
    float* ap = agg + (size_t)n * Hh + lane * 4;
    float4 acc = *(float4*)ap;
    for (int i = rs; i < re; i++) {
        float4 wv = *(const float4*)(Wc + (size_t)(i - c0) * Hh + lane * 4);
        float4 xv = *(const float4*)(xl + (size_t)esrc[i] * Hh + lane * 4);
        acc.x += wv.x * xv.x; acc.y += wv.y * xv.y;
        acc.z += wv.z * xv.z; acc.w += wv.w * xv.w;
    }
    *(float4*)ap = acc;
}

// ---------------- GraphNorm (fp32) ----------------
__global__ void gn_mean_kernel(const float* __restrict__ h, const int* __restrict__ gstart,
                               float* __restrict__ mean) {
    int g = blockIdx.x, c = threadIdx.x;
    int s = gstart[g], e = gstart[g + 1];
    float acc = 0.f;
    for (int n = s; n < e; n++) acc += h[(size_t)n * Hh + c];
    float cnt = (float)((e - s) > 1 ? (e - s) : 1);
    mean[(size_t)g * Hh + c] = acc / cnt;
}

__global__ void gn_out_kernel(const float* __restrict__ h, const float* __restrict__ mean,
                              const int* __restrict__ batch, const float* __restrict__ ms,
                              float* __restrict__ outp) {
    long i = (long)blockIdx.x * 256 + threadIdx.x;
    if (i >= (long)Nn * Hh) return;
    int n = (int)(i >> 8);
    int c = (int)(i & 255);
    outp[i] = h[i] - ms[c] * mean[(size_t)batch[n] * Hh + c];
}

__global__ void gn_rstd_kernel(const float* __restrict__ outp, const int* __restrict__ gstart,
                               float* __restrict__ rstd) {
    int g = blockIdx.x, c = threadIdx.x;
    int s = gstart[g], e = gstart[g + 1];
    float acc = 0.f;
    for (int n = s; n < e; n++) { float v = outp[(size_t)n * Hh + c]; acc += v * v; }
    float cnt = (float)((e - s) > 1 ? (e - s) : 1);
    rstd[(size_t)g * Hh + c] = rsqrtf(acc / cnt + EPSc);
}

__global__ void gn_apply_kernel(float* __restrict__ outp, const float* __restrict__ rstd,
                                const int* __restrict__ batch, const float* __restrict__ w,
                                const float* __restrict__ b) {
    long i = (long)blockIdx.x * 256 + threadIdx.x;
    if (i >= (long)Nn * Hh) return;
    int n = (int)(i >> 8);
    int c = (int)(i & 255);
    outp[i] = outp[i] * rstd[(size_t)batch[n] * Hh + c] * w[c] + b[c];
}

// =====================================================================================
extern "C" void kernel_launch(void* const* d_in, const int* in_sizes, int n_in,
                              void* d_out, int out_size, void* d_ws, size_t ws_size,
                              hipStream_t stream) {
    const int* x_idx      = (const int*)d_in[0];
    const int* edge_index = (const int*)d_in[2];
    const int* batch      = (const int*)d_in[3];
    const float* feature1 = (const float*)d_in[4];
    const float* feature2 = (const float*)d_in[5];
    const float* x_tab    = (const float*)d_in[6];
    const float* linx_w   = (const float*)d_in[8];
    const float* linx_b   = (const float*)d_in[9];
    const float* linx_g   = (const float*)d_in[10];
    const float* linx_be  = (const float*)d_in[11];
    const float* f1_w1    = (const float*)d_in[12];
    const float* f1_b1    = (const float*)d_in[13];
    const float* f1_g     = (const float*)d_in[14];
    const float* f1_be    = (const float*)d_in[15];
    const float* f1_w2    = (const float*)d_in[16];
    const float* f1_b2    = (const float*)d_in[17];
    const float* f2_w1    = (const float*)d_in[18];
    const float* f2_b1    = (const float*)d_in[19];
    const float* f2_g     = (const float*)d_in[20];
    const float* f2_be    = (const float*)d_in[21];
    const float* f2_w2    = (const float*)d_in[22];
    const float* f2_b2    = (const float*)d_in[23];
    const float* c1_rel_w  = (const float*)d_in[24];
    const float* c1_rel_b  = (const float*)d_in[25];
    const float* c1_root_w = (const float*)d_in[26];
    const float* c2_rel_w  = (const float*)d_in[27];
    const float* c2_rel_b  = (const float*)d_in[28];
    const float* c2_root_w = (const float*)d_in[29];
    const float* cat_w    = (const float*)d_in[30];
    const float* cat_b    = (const float*)d_in[31];
    const float* lins_w   = (const float*)d_in[32];
    const float* lins_b   = (const float*)d_in[33];
    const float* gn_w     = (const float*)d_in[34];
    const float* gn_b     = (const float*)d_in[35];
    const float* gn_ms    = (const float*)d_in[36];
    const float* fin_w    = (const float*)d_in[37];
    const float* fin_b    = (const float*)d_in[38];

    size_t NH = (size_t)Nn * Hh;
    char* p = (char*)d_ws;
    float* X  = (float*)p; p += NH * 4;
    float* B1 = (float*)p; p += NH * 4;
    float* B2 = (float*)p; p += NH * 4;
    float* B3 = (float*)d_out;          // h1 scratch; fully rewritten by final GEMM
    float* gmean = (float*)p; p += (size_t)Gc * Hh * 4;
    float* grstd = (float*)p; p += (size_t)Gc * Hh * 4;
    float* colsum = (float*)p; p += 256 * 4;
    float* colsq  = (float*)p; p += 256 * 4;
    int* gstart = (int*)p; p += 2048 * 4;
    int* deg    = (int*)p; p += Nn * 4;
    int* iscan  = (int*)p; p += Nn * 4;
    int* rowptr = (int*)p; p += (Nn + 256) * 4;
    int* cursor = (int*)p; p += Nn * 4;
    int* bsum   = (int*)p; p += 256 * 4;
    int* ebase  = (int*)p; p += 256 * 4;
    int* eid    = (int*)p; p += (size_t)Ee * 4;
    int* esrc   = (int*)p; p += (size_t)Ee * 4;
    // bf16 weight buffers, hi then lo
    ushortt* linxWh = (ushortt*)p; p += (size_t)4 * 65536 * 2;
    ushortt* convWh = (ushortt*)p; p += (size_t)16 * 65536 * 2;
    ushortt* catWh  = (ushortt*)p; p += (size_t)8 * 65536 * 2;
    ushortt* linsWh = (ushortt*)p; p += (size_t)12 * 65536 * 2;
    ushortt* finWh  = (ushortt*)p; p += (size_t)4 * 65536 * 2;
    ushortt* fw2Wh  = (ushortt*)p; p += (size_t)8 * 16384 * 2;
    ushortt* linxWl = (ushortt*)p; p += (size_t)4 * 65536 * 2;
    ushortt* convWl = (ushortt*)p; p += (size_t)16 * 65536 * 2;
    ushortt* catWl  = (ushortt*)p; p += (size_t)8 * 65536 * 2;
    ushortt* linsWl = (ushortt*)p; p += (size_t)12 * 65536 * 2;
    ushortt* finWl  = (ushortt*)p; p += (size_t)4 * 65536 * 2;
    ushortt* fw2Wl  = (ushortt*)p; p += (size_t)8 * 16384 * 2;
    // chunk buffers (fp32): Uc [CE,64] + Wc [CE,256]
    long availB = (long)ws_size - (long)(p - (char*)d_ws) - 1024;
    int CE = (int)(availB / ((Mm + Hh) * 4));
    if (CE > Ee) CE = Ee;
    if (CE < 8000) CE = 8000;
    float* Uc = (float*)p;
    float* Wc = Uc + (size_t)CE * Mm;

    long totNH = (long)NH;
    int blksNH = (int)((totNH + 255) / 256);
    int blksE = (Ee + 255) / 256;
    int blksN = (Nn + 255) / 256;

    embed_x_kernel<<<Nn, 256, 0, stream>>>(x_idx, x_tab, X);
    seg_bounds_kernel<<<(Gc + 256) / 256, 256, 0, stream>>>(batch, gstart);
    hipMemsetAsync(deg, 0, Nn * sizeof(int), stream);
    deg_hist_kernel<<<blksE, 256, 0, stream>>>(edge_index, deg);
    psum_block_kernel<<<NB, 256, 0, stream>>>(deg, iscan, bsum);
    scan_bsum_kernel<<<1, 64, 0, stream>>>(bsum, ebase, rowptr);
    finalize_rowptr_kernel<<<blksN, 256, 0, stream>>>(deg, iscan, ebase, rowptr);
    hipMemcpyAsync(cursor, rowptr, Nn * sizeof(int), hipMemcpyDeviceToDevice, stream);
    fill_eid_kernel<<<blksE, 256, 0, stream>>>(edge_index, cursor, eid, esrc);

    auto wcv = [&](const float* src, ushortt* dh, ushortt* dl, int nmat, int K, int dstLD,
                   long dstMS, int kOff, long srcMS) {
        long tot = (long)nmat * 256 * K;
        wconv_kernel<<<(int)((tot + 255) / 256), 256, 0, stream>>>(src, dh, dl, nmat, K, dstLD,
                                                                   dstMS, kOff, srcMS);
    };
    wcv(linx_w, linxWh, linxWl, 4, 256, 256, 65536, 0, 65536);
    wcv(c1_rel_w,  convWh,          convWl,          4, 256, 512, 262144, 0,   65536);
    wcv(c1_root_w, convWh,          convWl,          4, 256, 512, 262144, 256, 65536);
    wcv(c2_rel_w,  convWh + 131072, convWl + 131072, 4, 256, 512, 262144, 0,   65536);
    wcv(c2_root_w, convWh + 131072, convWl + 131072, 4, 256, 512, 262144, 256, 65536);
    wcv(cat_w, catWh, catWl, 4, 512, 512, 131072, 0, 131072);
    wcv(lins_w, linsWh, linsWl, 12, 256, 256, 65536, 0, 65536);
    wcv(fin_w, finWh, finWl, 4, 256, 256, 65536, 0, 65536);
    wcv(f1_w2, fw2Wh,         fw2Wl,         4, 64, 64, 32768, 0, 16384);
    wcv(f2_w2, fw2Wh + 16384, fw2Wl + 16384, 4, 64, 64, 32768, 0, 16384);

    dim3 gN((Nn + 127) / 128, 2);

    for (int l = 0; l < Lc; l++) {
        // T = x @ linx_w + b -> B1 ; xl = relu(BN(T)) -> X
        bgemm_kernel<<<gN, 256, 0, stream>>>(X, 256, nullptr, 0,
                                             linxWh + (size_t)l * 65536, linxWl + (size_t)l * 65536,
                                             linx_b + l * Hh, nullptr, B1, Nn, 256, 256, 0);
        hipMemsetAsync(colsum, 0, 512 * sizeof(float), stream);
        colstats_kernel<<<256, 256, 0, stream>>>(B1, totNH, colsum, colsq);
        bn_relu_kernel<<<blksNH, 256, 0, stream>>>(B1, X, colsum, colsq,
                                                   linx_g + l * Hh, linx_be + l * Hh,
                                                   1.f / Nn, totNH);

        for (int br = 0; br < 2; br++) {
            const float* fw1 = br == 0 ? f1_w1 + (size_t)l * F1c * Mm : f2_w1 + (size_t)l * 6 * Mm;
            const float* fb1 = br == 0 ? f1_b1 + l * Mm : f2_b1 + l * Mm;
            const float* fg  = br == 0 ? f1_g + l * Mm  : f2_g + l * Mm;
            const float* fbe = br == 0 ? f1_be + l * Mm : f2_be + l * Mm;
            const float* fb2 = br == 0 ? f1_b2 + l * Hh : f2_b2 + l * Hh;
            const float* feat = br == 0 ? feature1 : feature2;
            int Kf = br == 0 ? F1c : 6;
            const float* relb = br == 0 ? c1_rel_b + l * Hh : c2_rel_b + l * Hh;
            ushortt* fw2h = fw2Wh + (size_t)l * 32768 + (br ? 16384 : 0);
            ushortt* fw2l = fw2Wl + (size_t)l * 32768 + (br ? 16384 : 0);
            ushortt* cvh  = convWh + (size_t)l * 262144 + (br ? 131072 : 0);
            ushortt* cvl  = convWl + (size_t)l * 262144 + (br ? 131072 : 0);
            float* hbr = br == 0 ? B3 : B2;

            hipMemsetAsync(colsum, 0, 512 * sizeof(float), stream);
            feat_stats_kernel<<<256, 256, 0, stream>>>(feat, fw1, fb1, Kf, colsum, colsq);
            hipMemsetAsync(B1, 0, NH * sizeof(float), stream);
            for (int c0 = 0; c0 < Ee; c0 += CE) {
                int ec = Ee - c0 < CE ? Ee - c0 : CE;
                feat_bn_kernel<<<(ec * Mm + 255) / 256, 256, 0, stream>>>(
                    feat, fw1, fb1, Kf, colsum, colsq, fg, fbe, 1.f / Ee, eid, Uc, c0, ec);
                dim3 gc((ec + 127) / 128, 2);
                bgemm_kernel<<<gc, 256, 0, stream>>>(Uc, 64, nullptr, 0, fw2h, fw2l,
                                                     fb2, nullptr, Wc, ec, 64, 64, 1);
                gather_agg_kernel<<<(Nn * 64 + 255) / 256, 256, 0, stream>>>(
                    rowptr, esrc, Wc, X, B1, c0, c0 + ec);
            }
            // h_br = relu(agg @ rel_w + xl @ root_w + rel_b)
            bgemm_kernel<<<gN, 256, 0, stream>>>(B1, 256, X, 256, cvh, cvl,
                                                 relb, nullptr, hbr, Nn, 256, 512, 1);
        }

        // h = relu([h1,h2] @ cat_w + cat_b) + xl -> B1
        bgemm_kernel<<<gN, 256, 0, stream>>>(B3, 256, B2, 256,
                                             catWh + (size_t)l * 131072, catWl + (size_t)l * 131072,
                                             cat_b + l * Hh, X, B1, Nn, 256, 512, 1);
        // residual linears: B1 <-> B2
        float* cur = B1; float* oth = B2;
        for (int k = 0; k < NLc; k++) {
            bgemm_kernel<<<gN, 256, 0, stream>>>(cur, 256, nullptr, 0,
                                                 linsWh + ((size_t)l * NLc + k) * 65536,
                                                 linsWl + ((size_t)l * NLc + k) * 65536,
                                                 lins_b + ((size_t)l * NLc + k) * Hh, cur,
                                                 oth, Nn, 256, 256, 1);
            float* t = cur; cur = oth; oth = t;
        }
        // cur == B2. GraphNorm: mean -> out(B1) -> rstd -> apply in place
        gn_mean_kernel<<<Gc, 256, 0, stream>>>(cur, gstart, gmean);
        gn_out_kernel<<<blksNH, 256, 0, stream>>>(cur, gmean, batch, gn_ms + l * Hh, oth);
        gn_rstd_kernel<<<Gc, 256, 0, stream>>>(oth, gstart, grstd);
        gn_apply_kernel<<<blksNH, 256, 0, stream>>>(oth, grstd, batch, gn_w + l * Hh,
                                                    gn_b + l * Hh);
        // x_next = h @ fin_w + fin_b
        bgemm_kernel<<<gN, 256, 0, stream>>>(oth, 256, nullptr, 0,
                                             finWh + (size_t)l * 65536, finWl + (size_t)l * 65536,
                                             fin_b + l * Hh, nullptr,
                                             (l == Lc - 1) ? (float*)d_out : X,
                                             Nn, 256, 256, 0);
    }
}

// Round 6
// 7147.168 us; speedup vs baseline: 3.0566x; 1.2700x over previous
//
#include <hip/hip_runtime.h>
#include <cstdint>

constexpr int Nn = 60000;
constexpr int Ee = 240000;
constexpr int Hh = 256;
constexpr int Mm = 64;
constexpr int F1c = 12;
constexpr int Lc = 4;
constexpr int NLc = 3;
constexpr int Gc = 2000;
constexpr float EPSc = 1e-5f;
constexpr int NB = (Nn + 255) / 256;

typedef __attribute__((ext_vector_type(8))) short bf16x8;
typedef __attribute__((ext_vector_type(4))) float f32x4;
typedef __attribute__((ext_vector_type(4))) unsigned short u16x4;
typedef unsigned short ushortt;

__device__ __forceinline__ float bf2f(ushortt u) {
    union { unsigned int i; float f; } c; c.i = ((unsigned int)u) << 16; return c.f;
}
__device__ __forceinline__ ushortt f2bf(float f) {
    union { float f; unsigned int i; } c; c.f = f;
    unsigned int u = c.i;
    return (ushortt)((u + 0x7FFFu + ((u >> 16) & 1u)) >> 16);
}

// ---------------- embedding (fp32) ----------------
__global__ void embed_x_kernel(const int* __restrict__ xidx, const float* __restrict__ xtab,
                               float* __restrict__ x) {
    int n = blockIdx.x;
    int c = threadIdx.x;
    __shared__ int idx[9];
    if (c < 9) idx[c] = xidx[n * 9 + c];
    __syncthreads();
    float s = 0.f;
#pragma unroll
    for (int j = 0; j < 9; j++) s += xtab[idx[j] * Hh + c];
    x[(size_t)n * Hh + c] = s;
}

__global__ void seg_bounds_kernel(const int* __restrict__ batch, int* __restrict__ gstart) {
    int g = blockIdx.x * 256 + threadIdx.x;
    if (g > Gc) return;
    if (g == Gc) { gstart[Gc] = Nn; return; }
    int lo = 0, hi = Nn;
    while (lo < hi) { int mid = (lo + hi) >> 1; if (batch[mid] < g) lo = mid + 1; else hi = mid; }
    gstart[g] = lo;
}

// ---------------- CSR build ----------------
__global__ void deg_hist_kernel(const int* __restrict__ ei, int* __restrict__ deg) {
    int e = blockIdx.x * 256 + threadIdx.x;
    if (e >= Ee) return;
    atomicAdd(&deg[ei[Ee + e]], 1);
}

__global__ void psum_block_kernel(const int* __restrict__ deg, int* __restrict__ iscan,
                                  int* __restrict__ bsum) {
    __shared__ int s[256];
    int t = threadIdx.x;
    int i = blockIdx.x * 256 + t;
    int v = (i < Nn) ? deg[i] : 0;
    s[t] = v;
    __syncthreads();
    for (int off = 1; off < 256; off <<= 1) {
        int add = (t >= off) ? s[t - off] : 0;
        __syncthreads();
        s[t] += add;
        __syncthreads();
    }
    if (i < Nn) iscan[i] = s[t];
    if (t == 255) bsum[blockIdx.x] = s[255];
}

__global__ void scan_bsum_kernel(const int* __restrict__ bsum, int* __restrict__ ebase,
                                 int* __restrict__ rowptr) {
    if (threadIdx.x != 0 || blockIdx.x != 0) return;
    int run = 0;
    for (int b = 0; b < NB; b++) { ebase[b] = run; run += bsum[b]; }
    rowptr[Nn] = Ee;
}

__global__ void finalize_rowptr_kernel(const int* __restrict__ deg, const int* __restrict__ iscan,
                                       const int* __restrict__ ebase, int* __restrict__ rowptr) {
    int i = blockIdx.x * 256 + threadIdx.x;
    if (i >= Nn) return;
    rowptr[i] = ebase[i >> 8] + iscan[i] - deg[i];
}

__global__ void fill_eid_kernel(const int* __restrict__ ei, int* __restrict__ cursor,
                                int* __restrict__ eid, int* __restrict__ esrc) {
    int e = blockIdx.x * 256 + threadIdx.x;
    if (e >= Ee) return;
    int dst = ei[Ee + e];
    int pos = atomicAdd(&cursor[dst], 1);
    eid[pos] = e;
    esrc[pos] = ei[e];
}

// ------- weight transpose + hi/lo bf16 split, k packed for b128 fragments ---------
// packed k index within each 32-block: kp = ((k&15)>>2)*8 + ((k>>4)&1)*4 + (k&3)
__global__ void wconv_kernel(const float* __restrict__ src, ushortt* __restrict__ dstHi,
                             ushortt* __restrict__ dstLo,
                             int nmat, int K, int dstLD, long dstMS, int kOff, long srcMS) {
    long idx = (long)blockIdx.x * 256 + threadIdx.x;
    long tot = (long)nmat * 256 * K;
    if (idx >= tot) return;
    int k = (int)(idx % K);
    long t = idx / K;
    int c = (int)(t & 255);
    int m = (int)(t >> 8);
    float w = src[m * srcMS + (long)k * 256 + c];
    ushortt h = f2bf(w);
    int kp = (k & ~31) + (((k & 15) >> 2) << 3) + (((k >> 4) & 1) << 2) + (k & 3);
    long o = m * dstMS + (long)c * dstLD + kOff + kp;
    dstHi[o] = h;
    dstLo[o] = f2bf(w - bf2f(h));
}

// ---------------- Gram matrix of edge features: G = F^T F, s = colsum(F) ----------
template<int K>
__global__ void gram_kernel(const float* __restrict__ F, float* __restrict__ G,
                            float* __restrict__ s) {
    constexpr int NP = K * (K + 1) / 2;
    float a[NP];
    float sv[K];
#pragma unroll
    for (int t = 0; t < NP; t++) a[t] = 0.f;
#pragma unroll
    for (int i = 0; i < K; i++) sv[i] = 0.f;
    for (int r = blockIdx.x * 256 + threadIdx.x; r < Ee; r += gridDim.x * 256) {
        float f[K];
#pragma unroll
        for (int i = 0; i < K; i++) f[i] = F[(size_t)r * K + i];
        int t = 0;
#pragma unroll
        for (int i = 0; i < K; i++) {
            sv[i] += f[i];
#pragma unroll
            for (int j = 0; j <= i; j++) { a[t] += f[i] * f[j]; t++; }
        }
    }
#pragma unroll
    for (int t = 0; t < NP; t++)
        for (int off = 32; off > 0; off >>= 1) a[t] += __shfl_down(a[t], off, 64);
#pragma unroll
    for (int i = 0; i < K; i++)
        for (int off = 32; off > 0; off >>= 1) sv[i] += __shfl_down(sv[i], off, 64);
    if ((threadIdx.x & 63) == 0) {
        int t = 0;
#pragma unroll
        for (int i = 0; i < K; i++) {
#pragma unroll
            for (int j = 0; j <= i; j++) {
                atomicAdd(&G[i * K + j], a[t]);
                if (i != j) atomicAdd(&G[j * K + i], a[t]);
                t++;
            }
            atomicAdd(&s[i], sv[i]);
        }
    }
}

// ------- BN stats from Gram: sum = s.w + E b ; sumsq = w^T G w + 2b(s.w) + E b^2 ---
__global__ void gram_stats_kernel(const float* __restrict__ G, const float* __restrict__ s,
                                  const float* __restrict__ W, const float* __restrict__ b,
                                  int K, float Ecnt, float* __restrict__ colsum,
                                  float* __restrict__ colsq) {
    int m = threadIdx.x;   // 64 threads
    float wm[F1c];
    for (int i = 0; i < K; i++) wm[i] = W[i * Mm + m];
    float sw = 0.f;
    for (int i = 0; i < K; i++) sw += s[i] * wm[i];
    float q = 0.f;
    for (int i = 0; i < K; i++) {
        float gi = 0.f;
        for (int j = 0; j < K; j++) gi += G[i * K + j] * wm[j];
        q += wm[i] * gi;
    }
    colsum[m] = sw + Ecnt * b[m];
    colsq[m] = q + 2.f * b[m] * sw + Ecnt * b[m] * b[m];
}

// ---------------- column stats over fp32 [rows, 256] (node BN) --------------------
__global__ void colstats_kernel(const float* __restrict__ A, long total,
                                float* __restrict__ sum, float* __restrict__ sq) {
    long i0 = (long)blockIdx.x * blockDim.x + threadIdx.x;
    long stride = (long)gridDim.x * blockDim.x;
    float s = 0.f, q = 0.f;
    for (long i = i0; i < total; i += stride) { float v = A[i]; s += v; q += v * v; }
    int col = (int)(i0 & 255);
    atomicAdd(&sum[col], s);
    atomicAdd(&sq[col], q);
}

__global__ void bn_relu_kernel(const float* __restrict__ A, float* __restrict__ outp,
                               const float* __restrict__ sum, const float* __restrict__ sq,
                               const float* __restrict__ g, const float* __restrict__ be,
                               float rinv, long total) {
    long i = (long)blockIdx.x * 256 + threadIdx.x;
    if (i >= total) return;
    int col = (int)(i & 255);
    float m = sum[col] * rinv;
    float var = sq[col] * rinv - m * m;
    float v = (A[i] - m) * rsqrtf(var + EPSc) * g[col] + be[col];
    outp[i] = fmaxf(v, 0.f);
}

// ------- per-chunk dst-sorted: Uc = relu(BN(feat[eid]@W1+b)) fp32 ------------------
__global__ void feat_bn_kernel(const float* __restrict__ F, const float* __restrict__ W,
                               const float* __restrict__ b, int K,
                               const float* __restrict__ sum, const float* __restrict__ sq,
                               const float* __restrict__ g, const float* __restrict__ be,
                               float rinv, const int* __restrict__ eid,
                               float* __restrict__ Uc, int c0, int ec) {
    __shared__ float Wsh[F1c * Mm];
    __shared__ float bsh[Mm];
    int tid = threadIdx.x;
    for (int i = tid; i < K * Mm; i += 256) Wsh[i] = W[i];
    if (tid < Mm) bsh[tid] = b[tid];
    __syncthreads();
    int i = blockIdx.x * 256 + tid;
    if (i >= ec * Mm) return;
    int rl = i >> 6, m = i & 63;
    const float* fr = F + (size_t)eid[c0 + rl] * K;
    float u = bsh[m];
    for (int k = 0; k < K; k++) u += fr[k] * Wsh[k * Mm + m];
    float mu = sum[m] * rinv;
    float var = sq[m] * rinv - mu * mu;
    float v = (u - mu) * rsqrtf(var + EPSc) * g[m] + be[m];
    Uc[i] = fmaxf(v, 0.f);
}

// ---------------- split-bf16 (hi/lo 3-term) MFMA GEMM v2 --------------------------
// BK=32, 32KB LDS, packed-k layout: one ds_read_b128 per fragment.
// LDS row (128B): [64B hi-packed | 64B lo-packed], XOR swizzle ((row&7)<<4).
__global__ __launch_bounds__(256, 3) void bgemm_kernel(
    const float* __restrict__ A1, int lda1, const float* __restrict__ A2, int lda2,
    const ushortt* __restrict__ Whi, const ushortt* __restrict__ Wlo,
    const float* __restrict__ bias, const float* __restrict__ res,
    float* __restrict__ C, int rows, int K1, int Ktot, int do_relu) {
    __shared__ char lds[32768];
    char* As = lds;
    char* Ws = lds + 16384;
    int tid = threadIdx.x;
    int lane = tid & 63;
    int wave = tid >> 6;
    int wrow0 = (wave >> 1) * 64;
    int wcol0 = (wave & 1) * 64;
    int r0 = blockIdx.x * 128;
    int j0 = blockIdx.y * 128;
    int l15 = lane & 15;
    int l4 = lane >> 4;

    f32x4 acc[4][4];
#pragma unroll
    for (int i = 0; i < 4; i++)
#pragma unroll
        for (int j = 0; j < 4; j++) acc[i][j] = (f32x4){0.f, 0.f, 0.f, 0.f};

    for (int kt = 0; kt < Ktot; kt += 32) {
        const float* A; int lda; int koff;
        if (kt < K1) { A = A1; lda = lda1; koff = kt; }
        else         { A = A2; lda = lda2; koff = kt - K1; }
        // stage A: 128 rows x 32 k fp32 -> hi/lo packed bf16
#pragma unroll
        for (int p = 0; p < 4; p++) {
            int fid = p * 256 + tid;       // 1024 float4
            int row = fid >> 3;            // 8 float4 per row
            int k4 = (fid & 7) * 4;
            int rg = r0 + row; if (rg >= rows) rg = rows - 1;
            float4 v = *(const float4*)(A + (size_t)rg * lda + koff + k4);
            u16x4 hi, lo;
            hi[0] = f2bf(v.x); lo[0] = f2bf(v.x - bf2f(hi[0]));
            hi[1] = f2bf(v.y); lo[1] = f2bf(v.y - bf2f(hi[1]));
            hi[2] = f2bf(v.z); lo[2] = f2bf(v.z - bf2f(hi[2]));
            hi[3] = f2bf(v.w); lo[3] = f2bf(v.w - bf2f(hi[3]));
            int off = (((k4 & 15) >> 2) << 4) + ((k4 >> 4) << 3);  // g*16 + sub*8
            int sw = (row & 7) << 4;
            *(u16x4*)(As + ((row * 128 + off) ^ sw)) = hi;
            *(u16x4*)(As + ((row * 128 + off + 64) ^ sw)) = lo;
        }
        // stage W: 128 cols x 32 k (pre-packed global) hi/lo
#pragma unroll
        for (int p = 0; p < 2; p++) {
            int fid = p * 256 + tid;       // 512 uint4
            int row = fid >> 2;            // 4 uint4 per row
            int b16 = (fid & 3) * 16;
            size_t srcoff = ((size_t)(j0 + row) * Ktot + kt) * 2 + b16;
            uint4 vh = *(const uint4*)((const char*)Whi + srcoff);
            uint4 vl = *(const uint4*)((const char*)Wlo + srcoff);
            int sw = (row & 7) << 4;
            *(uint4*)(Ws + ((row * 128 + b16) ^ sw)) = vh;
            *(uint4*)(Ws + ((row * 128 + b16 + 64) ^ sw)) = vl;
        }
        __syncthreads();

        bf16x8 ah[4], al[4], bh[4], bl[4];
#pragma unroll
        for (int i = 0; i < 4; i++) {
            int row = wrow0 + i * 16 + l15;
            int sw = (row & 7) << 4;
            ah[i] = *(const bf16x8*)(As + ((row * 128 + l4 * 16) ^ sw));
            al[i] = *(const bf16x8*)(As + ((row * 128 + l4 * 16 + 64) ^ sw));
        }
#pragma unroll
        for (int j = 0; j < 4; j++) {
            int row = wcol0 + j * 16 + l15;
            int sw = (row & 7) << 4;
            bh[j] = *(const bf16x8*)(Ws + ((row * 128 + l4 * 16) ^ sw));
            bl[j] = *(const bf16x8*)(Ws + ((row * 128 + l4 * 16 + 64) ^ sw));
        }
#pragma unroll
        for (int i = 0; i < 4; i++)
#pragma unroll
            for (int j = 0; j < 4; j++) {
                acc[i][j] = __builtin_amdgcn_mfma_f32_16x16x32_bf16(ah[i], bh[j], acc[i][j], 0, 0, 0);
                acc[i][j] = __builtin_amdgcn_mfma_f32_16x16x32_bf16(ah[i], bl[j], acc[i][j], 0, 0, 0);
                acc[i][j] = __builtin_amdgcn_mfma_f32_16x16x32_bf16(al[i], bh[j], acc[i][j], 0, 0, 0);
            }
        __syncthreads();
    }

#pragma unroll
    for (int i = 0; i < 4; i++) {
#pragma unroll
        for (int r = 0; r < 4; r++) {
            int row = r0 + wrow0 + i * 16 + l4 * 4 + r;
            if (row >= rows) continue;
#pragma unroll
            for (int j = 0; j < 4; j++) {
                int col = j0 + wcol0 + j * 16 + l15;
                float v = acc[i][j][r] + bias[col];
                if (do_relu) v = fmaxf(v, 0.f);
                if (res) v += res[(size_t)row * 256 + col];
                C[(size_t)row * 256 + col] = v;
            }
        }
    }
}

// ------- gather-aggregate (fp32, no atomics) ---------------------------------------
__global__ __launch_bounds__(256) void gather_agg_kernel(
    const int* __restrict__ rowptr, const int* __restrict__ esrc,
    const float* __restrict__ Wc, const float* __restrict__ xl,
    float* __restrict__ agg, int c0, int c1) {
    int n = (blockIdx.x * 256 + threadIdx.x) >> 6;
    if (n >= Nn) return;
    int lane = threadIdx.x & 63;
    int rs = rowptr[n], re = rowptr[n + 1];
    if (rs < c0) rs = c0;
    if (re > c1) re = c1;
    if (rs >= re) return;
    float* ap = agg + (size_t)n * Hh + lane * 4;
    float4 acc = *(float4*)ap;
    for (int i = rs; i < re; i++) {
        float4 wv = *(const float4*)(Wc + (size_t)(i - c0) * Hh + lane * 4);
        float4 xv = *(const float4*)(xl + (size_t)esrc[i] * Hh + lane * 4);
        acc.x += wv.x * xv.x; acc.y += wv.y * xv.y;
        acc.z += wv.z * xv.z; acc.w += wv.w * xv.w;
    }
    *(float4*)ap = acc;
}

// ---------------- GraphNorm (fp32) ----------------
__global__ void gn_mean_kernel(const float* __restrict__ h, const int* __restrict__ gstart,
                               float* __restrict__ mean) {
    int g = blockIdx.x, c = threadIdx.x;
    int s = gstart[g], e = gstart[g + 1];
    float acc = 0.f;
    for (int n = s; n < e; n++) acc += h[(size_t)n * Hh + c];
    float cnt = (float)((e - s) > 1 ? (e - s) : 1);
    mean[(size_t)g * Hh + c] = acc / cnt;
}

__global__ void gn_out_kernel(const float* __restrict__ h, const float* __restrict__ mean,
                              const int* __restrict__ batch, const float* __restrict__ ms,
                              float* __restrict__ outp) {
    long i = (long)blockIdx.x * 256 + threadIdx.x;
    if (i >= (long)Nn * Hh) return;
    int n = (int)(i >> 8);
    int c = (int)(i & 255);
    outp[i] = h[i] - ms[c] * mean[(size_t)batch[n] * Hh + c];
}

__global__ void gn_rstd_kernel(const float* __restrict__ outp, const int* __restrict__ gstart,
                               float* __restrict__ rstd) {
    int g = blockIdx.x, c = threadIdx.x;
    int s = gstart[g], e = gstart[g + 1];
    float acc = 0.f;
    for (int n = s; n < e; n++) { float v = outp[(size_t)n * Hh + c]; acc += v * v; }
    float cnt = (float)((e - s) > 1 ? (e - s) : 1);
    rstd[(size_t)g * Hh + c] = rsqrtf(acc / cnt + EPSc);
}

__global__ void gn_apply_kernel(float* __restrict__ outp, const float* __restrict__ rstd,
                                const int* __restrict__ batch, const float* __restrict__ w,
                                const float* __restrict__ b) {
    long i = (long)blockIdx.x * 256 + threadIdx.x;
    if (i >= (long)Nn * Hh) return;
    int n = (int)(i >> 8);
    int c = (int)(i & 255);
    outp[i] = outp[i] * rstd[(size_t)batch[n] * Hh + c] * w[c] + b[c];
}

// =====================================================================================
extern "C" void kernel_launch(void* const* d_in, const int* in_sizes, int n_in,
                              void* d_out, int out_size, void* d_ws, size_t ws_size,
                              hipStream_t stream) {
    const int* x_idx      = (const int*)d_in[0];
    const int* edge_index = (const int*)d_in[2];
    const int* batch      = (const int*)d_in[3];
    const float* feature1 = (const float*)d_in[4];
    const float* feature2 = (const float*)d_in[5];
    const float* x_tab    = (const float*)d_in[6];
    const float* linx_w   = (const float*)d_in[8];
    const float* linx_b   = (const float*)d_in[9];
    const float* linx_g   = (const float*)d_in[10];
    const float* linx_be  = (const float*)d_in[11];
    const float* f1_w1    = (const float*)d_in[12];
    const float* f1_b1    = (const float*)d_in[13];
    const float* f1_g     = (const float*)d_in[14];
    const float* f1_be    = (const float*)d_in[15];
    const float* f1_w2    = (const float*)d_in[16];
    const float* f1_b2    = (const float*)d_in[17];
    const float* f2_w1    = (const float*)d_in[18];
    const float* f2_b1    = (const float*)d_in[19];
    const float* f2_g     = (const float*)d_in[20];
    const float* f2_be    = (const float*)d_in[21];
    const float* f2_w2    = (const float*)d_in[22];
    const float* f2_b2    = (const float*)d_in[23];
    const float* c1_rel_w  = (const float*)d_in[24];
    const float* c1_rel_b  = (const float*)d_in[25];
    const float* c1_root_w = (const float*)d_in[26];
    const float* c2_rel_w  = (const float*)d_in[27];
    const float* c2_rel_b  = (const float*)d_in[28];
    const float* c2_root_w = (const float*)d_in[29];
    const float* cat_w    = (const float*)d_in[30];
    const float* cat_b    = (const float*)d_in[31];
    const float* lins_w   = (const float*)d_in[32];
    const float* lins_b   = (const float*)d_in[33];
    const float* gn_w     = (const float*)d_in[34];
    const float* gn_b     = (const float*)d_in[35];
    const float* gn_ms    = (const float*)d_in[36];
    const float* fin_w    = (const float*)d_in[37];
    const float* fin_b    = (const float*)d_in[38];

    size_t NH = (size_t)Nn * Hh;
    char* p = (char*)d_ws;
    float* X  = (float*)p; p += NH * 4;
    float* B1 = (float*)p; p += NH * 4;
    float* B2 = (float*)p; p += NH * 4;
    float* B3 = (float*)d_out;          // h1 scratch; fully rewritten by final GEMM
    float* gmean = (float*)p; p += (size_t)Gc * Hh * 4;
    float* grstd = (float*)p; p += (size_t)Gc * Hh * 4;
    float* colsum = (float*)p; p += 256 * 4;
    float* colsq  = (float*)p; p += 256 * 4;
    float* G1 = (float*)p; p += 160 * 4;     // 144 used
    float* s1 = (float*)p; p += 16 * 4;
    float* G2 = (float*)p; p += 48 * 4;      // 36 used
    float* s2 = (float*)p; p += 16 * 4;
    int* gstart = (int*)p; p += 2048 * 4;
    int* deg    = (int*)p; p += Nn * 4;
    int* iscan  = (int*)p; p += Nn * 4;
    int* rowptr = (int*)p; p += (Nn + 256) * 4;
    int* cursor = (int*)p; p += Nn * 4;
    int* bsum   = (int*)p; p += 256 * 4;
    int* ebase  = (int*)p; p += 256 * 4;
    int* eid    = (int*)p; p += (size_t)Ee * 4;
    int* esrc   = (int*)p; p += (size_t)Ee * 4;
    // bf16 weight buffers (packed-k, transposed), hi then lo
    ushortt* linxWh = (ushortt*)p; p += (size_t)4 * 65536 * 2;
    ushortt* convWh = (ushortt*)p; p += (size_t)16 * 65536 * 2;
    ushortt* catWh  = (ushortt*)p; p += (size_t)8 * 65536 * 2;
    ushortt* linsWh = (ushortt*)p; p += (size_t)12 * 65536 * 2;
    ushortt* finWh  = (ushortt*)p; p += (size_t)4 * 65536 * 2;
    ushortt* fw2Wh  = (ushortt*)p; p += (size_t)8 * 16384 * 2;
    ushortt* linxWl = (ushortt*)p; p += (size_t)4 * 65536 * 2;
    ushortt* convWl = (ushortt*)p; p += (size_t)16 * 65536 * 2;
    ushortt* catWl  = (ushortt*)p; p += (size_t)8 * 65536 * 2;
    ushortt* linsWl = (ushortt*)p; p += (size_t)12 * 65536 * 2;
    ushortt* finWl  = (ushortt*)p; p += (size_t)4 * 65536 * 2;
    ushortt* fw2Wl  = (ushortt*)p; p += (size_t)8 * 16384 * 2;
    // chunk buffers (fp32): Uc [CE,64] + Wc [CE,256]
    long availB = (long)ws_size - (long)(p - (char*)d_ws) - 1024;
    int CE = (int)(availB / ((Mm + Hh) * 4));
    if (CE > Ee) CE = Ee;
    if (CE < 8000) CE = 8000;
    float* Uc = (float*)p;
    float* Wc = Uc + (size_t)CE * Mm;

    long totNH = (long)NH;
    int blksNH = (int)((totNH + 255) / 256);
    int blksE = (Ee + 255) / 256;
    int blksN = (Nn + 255) / 256;

    embed_x_kernel<<<Nn, 256, 0, stream>>>(x_idx, x_tab, X);
    seg_bounds_kernel<<<(Gc + 256) / 256, 256, 0, stream>>>(batch, gstart);
    hipMemsetAsync(deg, 0, Nn * sizeof(int), stream);
    deg_hist_kernel<<<blksE, 256, 0, stream>>>(edge_index, deg);
    psum_block_kernel<<<NB, 256, 0, stream>>>(deg, iscan, bsum);
    scan_bsum_kernel<<<1, 64, 0, stream>>>(bsum, ebase, rowptr);
    finalize_rowptr_kernel<<<blksN, 256, 0, stream>>>(deg, iscan, ebase, rowptr);
    hipMemcpyAsync(cursor, rowptr, Nn * sizeof(int), hipMemcpyDeviceToDevice, stream);
    fill_eid_kernel<<<blksE, 256, 0, stream>>>(edge_index, cursor, eid, esrc);

    // Gram matrices (once)
    hipMemsetAsync(G1, 0, 240 * sizeof(float), stream);   // G1,s1,G2,s2 contiguous
    gram_kernel<F1c><<<64, 256, 0, stream>>>(feature1, G1, s1);
    gram_kernel<6><<<64, 256, 0, stream>>>(feature2, G2, s2);

    auto wcv = [&](const float* src, ushortt* dh, ushortt* dl, int nmat, int K, int dstLD,
                   long dstMS, int kOff, long srcMS) {
        long tot = (long)nmat * 256 * K;
        wconv_kernel<<<(int)((tot + 255) / 256), 256, 0, stream>>>(src, dh, dl, nmat, K, dstLD,
                                                                   dstMS, kOff, srcMS);
    };
    wcv(linx_w, linxWh, linxWl, 4, 256, 256, 65536, 0, 65536);
    wcv(c1_rel_w,  convWh,          convWl,          4, 256, 512, 262144, 0,   65536);
    wcv(c1_root_w, convWh,          convWl,          4, 256, 512, 262144, 256, 65536);
    wcv(c2_rel_w,  convWh + 131072, convWl + 131072, 4, 256, 512, 262144, 0,   65536);
    wcv(c2_root_w, convWh + 131072, convWl + 131072, 4, 256, 512, 262144, 256, 65536);
    wcv(cat_w, catWh, catWl, 4, 512, 512, 131072, 0, 131072);
    wcv(lins_w, linsWh, linsWl, 12, 256, 256, 65536, 0, 65536);
    wcv(fin_w, finWh, finWl, 4, 256, 256, 65536, 0, 65536);
    wcv(f1_w2, fw2Wh,         fw2Wl,         4, 64, 64, 32768, 0, 16384);
    wcv(f2_w2, fw2Wh + 16384, fw2Wl + 16384, 4, 64, 64, 32768, 0, 16384);

    dim3 gN((Nn + 127) / 128, 2);

    for (int l = 0; l < Lc; l++) {
        // T = x @ linx_w + b -> B1 ; xl = relu(BN(T)) -> X
        bgemm_kernel<<<gN, 256, 0, stream>>>(X, 256, nullptr, 0,
                                             linxWh + (size_t)l * 65536, linxWl + (size_t)l * 65536,
                                             linx_b + l * Hh, nullptr, B1, Nn, 256, 256, 0);
        hipMemsetAsync(colsum, 0, 512 * sizeof(float), stream);
        colstats_kernel<<<256, 256, 0, stream>>>(B1, totNH, colsum, colsq);
        bn_relu_kernel<<<blksNH, 256, 0, stream>>>(B1, X, colsum, colsq,
                                                   linx_g + l * Hh, linx_be + l * Hh,
                                                   1.f / Nn, totNH);

        for (int br = 0; br < 2; br++) {
            const float* fw1 = br == 0 ? f1_w1 + (size_t)l * F1c * Mm : f2_w1 + (size_t)l * 6 * Mm;
            const float* fb1 = br == 0 ? f1_b1 + l * Mm : f2_b1 + l * Mm;
            const float* fg  = br == 0 ? f1_g + l * Mm  : f2_g + l * Mm;
            const float* fbe = br == 0 ? f1_be + l * Mm : f2_be + l * Mm;
            const float* fb2 = br == 0 ? f1_b2 + l * Hh : f2_b2 + l * Hh;
            const float* feat = br == 0 ? feature1 : feature2;
            int Kf = br == 0 ? F1c : 6;
            const float* Gg = br == 0 ? G1 : G2;
            const float* sg = br == 0 ? s1 : s2;
            const float* relb = br == 0 ? c1_rel_b + l * Hh : c2_rel_b + l * Hh;
            ushortt* fw2h = fw2Wh + (size_t)l * 32768 + (br ? 16384 : 0);
            ushortt* fw2l = fw2Wl + (size_t)l * 32768 + (br ? 16384 : 0);
            ushortt* cvh  = convWh + (size_t)l * 262144 + (br ? 131072 : 0);
            ushortt* cvl  = convWl + (size_t)l * 262144 + (br ? 131072 : 0);
            float* hbr = br == 0 ? B3 : B2;

            // BN stats over edges via Gram closed form (replaces 197us feat_stats)
            gram_stats_kernel<<<1, 64, 0, stream>>>(Gg, sg, fw1, fb1, Kf, (float)Ee,
                                                    colsum, colsq);
            hipMemsetAsync(B1, 0, NH * sizeof(float), stream);
            for (int c0 = 0; c0 < Ee; c0 += CE) {
                int ec = Ee - c0 < CE ? Ee - c0 : CE;
                feat_bn_kernel<<<(ec * Mm + 255) / 256, 256, 0, stream>>>(
                    feat, fw1, fb1, Kf, colsum, colsq, fg, fbe, 1.f / Ee, eid, Uc, c0, ec);
                dim3 gc((ec + 127) / 128, 2);
                bgemm_kernel<<<gc, 256, 0, stream>>>(Uc, 64, nullptr, 0, fw2h, fw2l,
                                                     fb2, nullptr, Wc, ec, 64, 64, 1);
                gather_agg_kernel<<<(Nn * 64 + 255) / 256, 256, 0, stream>>>(
                    rowptr, esrc, Wc, X, B1, c0, c0 + ec);
            }
            // h_br = relu(agg @ rel_w + xl @ root_w + rel_b)
            bgemm_kernel<<<gN, 256, 0, stream>>>(B1, 256, X, 256, cvh, cvl,
                                                 relb, nullptr, hbr, Nn, 256, 512, 1);
        }

        // h = relu([h1,h2] @ cat_w + cat_b) + xl -> B1
        bgemm_kernel<<<gN, 256, 0, stream>>>(B3, 256, B2, 256,
                                             catWh + (size_t)l * 131072, catWl + (size_t)l * 131072,
                                             cat_b + l * Hh, X, B1, Nn, 256, 512, 1);
        // residual linears: B1 <-> B2
        float* cur = B1; float* oth = B2;
        for (int k = 0; k < NLc; k++) {
            bgemm_kernel<<<gN, 256, 0, stream>>>(cur, 256, nullptr, 0,
                                                 linsWh + ((size_t)l * NLc + k) * 65536,
                                                 linsWl + ((size_t)l * NLc + k) * 65536,
                                                 lins_b + ((size_t)l * NLc + k) * Hh, cur,
                                                 oth, Nn, 256, 256, 1);
            float* t = cur; cur = oth; oth = t;
        }
        // cur == B2. GraphNorm: mean -> out(B1) -> rstd -> apply in place
        gn_mean_kernel<<<Gc, 256, 0, stream>>>(cur, gstart, gmean);
        gn_out_kernel<<<blksNH, 256, 0, stream>>>(cur, gmean, batch, gn_ms + l * Hh, oth);
        gn_rstd_kernel<<<Gc, 256, 0, stream>>>(oth, gstart, grstd);
        gn_apply_kernel<<<blksNH, 256, 0, stream>>>(oth, grstd, batch, gn_w + l * Hh,
                                                    gn_b + l * Hh);
        // x_next = h @ fin_w + fin_b
        bgemm_kernel<<<gN, 256, 0, stream>>>(oth, 256, nullptr, 0,
                                             finWh + (size_t)l * 65536, finWl + (size_t)l * 65536,
                                             fin_b + l * Hh, nullptr,
                                             (l == Lc - 1) ? (float*)d_out : X,
                                             Nn, 256, 256, 0);
    }
}